// Round 4
// baseline (574.198 us; speedup 1.0000x reference)
//
#include <hip/hip_runtime.h>
#include <cstdint>

#define HH 72
#define NR 4           // rows per block
#define NTH 576        // 9 waves, 2 tiles/wave
#define NBLK 512       // 2 blocks per CU -> two independent barrier domains/CU
#define TT 512

typedef __attribute__((ext_vector_type(8))) _Float16 half8;
typedef __attribute__((ext_vector_type(4))) float f32x4;

#if __has_builtin(__builtin_amdgcn_exp2f)
#define EXP2(x) __builtin_amdgcn_exp2f(x)
#else
#define EXP2(x) exp2f(x)
#endif
#if __has_builtin(__builtin_amdgcn_rcpf)
#define RCP(x) __builtin_amdgcn_rcpf(x)
#else
#define RCP(x) (1.0f/(x))
#endif

__device__ __forceinline__ float fsig(float x) {
  float e = EXP2(x * -1.442695040888963f);
  return RCP(1.0f + e);
}
__device__ __forceinline__ float ftanh(float x) {
  float e = EXP2(x * -2.885390081777927f);
  return fmaf(2.0f, RCP(1.0f + e), -1.0f);
}

// fp32 -> fp16 bits (RNE via v_cvt_f16_f32)
__device__ __forceinline__ unsigned short f2h(float v) {
  union { _Float16 h; unsigned short u; } cv;
  cv.h = (_Float16)v;
  return cv.u;
}

// fragment ushort index for contraction-dim k, batch col m (0..3).
// Layout [kt*4+q][m=4][8]: 8 contiguous fp16 -> one ds_read_b128 per (group,m).
__device__ __forceinline__ int bidx(int k, int m) {
  return ((k >> 5)*4 + ((k >> 3) & 3))*32 + m*8 + (k & 7);
}

__device__ __forceinline__ float cellUpd(float ig, float fg, float gg, float og, float& c) {
  c = fmaf(fsig(fg), c, fsig(ig)*ftanh(gg));
  return fsig(og)*ftanh(c);
}

// accumulate 2 rows: A[j] += W_ * P_[j]
#define FMA2(A, W_, P_) { \
  const float2 _fa = *(const float2*)(P_); \
  A[0] = fmaf((W_), _fa.x, A[0]); A[1] = fmaf((W_), _fa.y, A[1]); }

// counting sort of rows by h_lens (ascending) -> co-resident blocks get
// adjacent-length groups (see pgrp mapping in cfm_main)
__global__ void cfm_sort(const int* __restrict__ h_lens, int* __restrict__ perm) {
  __shared__ int hist[257];
  __shared__ int offs[257];
  const int t = threadIdx.x; // 256
  for (int i = t; i < 257; i += 256) hist[i] = 0;
  __syncthreads();
  for (int i = t; i < 2048; i += 256) {
    int bkt = min(max(h_lens[i] - 256, 0), 256);
    atomicAdd(&hist[bkt], 1);
  }
  __syncthreads();
  if (t == 0) { int s = 0; for (int i = 0; i < 257; ++i) { offs[i] = s; s += hist[i]; } }
  __syncthreads();
  for (int i = t; i < 2048; i += 256) {
    int bkt = min(max(h_lens[i] - 256, 0), 256);
    int pos = atomicAdd(&offs[bkt], 1);
    perm[pos] = i;
  }
}

// 4 rows/block, 512 blocks -> 2 blocks/CU with independent barriers.
// Per-wave step program identical to the 269us NR=8 version; B cols read col&3
// (4-way broadcast). Chains of the two co-resident blocks overlap in time.
__global__ __launch_bounds__(NTH, 4)   // 4 waves/EU min -> VGPR cap 128 (need ~64)
void cfm_main(const float* __restrict__ x, const float* __restrict__ rnn,
              const float* __restrict__ deltas, const int* __restrict__ h_lens,
              const float* __restrict__ W_ih, const float* __restrict__ W_hh,
              const float* __restrict__ b_ih, const float* __restrict__ b_hh,
              const float* __restrict__ eW1, const float* __restrict__ eb1,
              const float* __restrict__ eW2, const float* __restrict__ eb2,
              const float* __restrict__ eW3, const float* __restrict__ eb3,
              const float* __restrict__ dW1, const float* __restrict__ db1,
              const float* __restrict__ dW2, const float* __restrict__ db2,
              const float* __restrict__ dW3, const float* __restrict__ db3,
              const int* __restrict__ perm, float* __restrict__ out)
{
  __shared__ __align__(16) unsigned short hF[2][384]; // fp16 [h|xt|pad] B-frags, dbuf
  __shared__ __align__(16) float gS[1152];            // enc z1S / dec d2S  [n][4]
  __shared__ __align__(16) float rnnS[1168];          // rnn chunk [4][292]; enc z2S / dec d1S
  __shared__ __align__(16) float snapP[NR][HH];
  __shared__ __align__(16) float snapC[NR][HH];
  __shared__ __align__(16) float hS[HH*NR];           // decoder dec_in [u][r]
  __shared__ __align__(16) float xS[8*NR];            // [k][r]
  __shared__ int brS[NR];
  __shared__ int idxS[NR];
  __shared__ float dS[NR];

  const int t  = threadIdx.x;
  const int bb = blockIdx.x;
  // blocks c and c+256 land on the same CU (round-robin over 8 XCDs x 32 CUs).
  // Give them ADJACENT sorted-length groups -> near-equal runtimes -> ~full
  // co-residency for chain overlap.
  const int pgrp = (bb < 256) ? (2*bb) : (2*(bb - 256) + 1);

  for (int i = t; i < 384; i += NTH) ((unsigned*)hF)[i] = 0;  // zero both buffers (pads!)

  if (t < NR) {
    int row = perm ? perm[pgrp*NR + t] : (pgrp*NR + t);
    brS[t]  = row;
    idxS[t] = h_lens[row] - 1;   // in [255, 511]
  }
  __syncthreads();

  int maxIdx = idxS[0];
  #pragma unroll
  for (int r = 1; r < NR; ++r) maxIdx = max(maxIdx, idxS[r]);

  const int lane = t & 63;
  const int wv   = t >> 6;                 // 0..8, tiles {2wv, 2wv+1}
  const int col  = lane & 15;
  const int q_a  = lane >> 4;
  const int cL   = col & 3;                // batch col (4-way broadcast dup)
  const int gHi  = col >> 3;               // which of my wave's 2 tiles
  const int uA   = 4*(2*wv + gHi) + q_a;   // unit owned
  const int cidxE  = idxS[cL];
  const int cidxm1 = cidxE - 1;
  const int ibA  = bidx(uA, cL);
  const int bOff0 = (0*4 + q_a)*32 + cL*8; // broadcast read: col&3
  const int bOff1 = (1*4 + q_a)*32 + cL*8;
  const int bOff2 = (2*4 + q_a)*32 + cL*8;
  float cstA = 0.f;
  float hvP = 0.f, hvC = 0.f;

  // prefetch rnn chunk 0 into regs (t<288: 1 float4/thread = 4 rows * 288 floats)
  const int pfR = t / 72;                  // 0..3 (for t<288)
  const int pfP = t - pfR*72;              // 0..71
  const bool doPf = (t < 288);
  const float4* rnnRow = doPf ? ((const float4*)(rnn + (size_t)brS[pfR]*4608) + pfP)
                              : (const float4*)rnn;
  float4 pf = doPf ? rnnRow[0] : float4{0,0,0,0};

  // xt staging lanes: 36 values/step (4 rows x 9 k)
  const bool doXt = (t < 36);
  int xtDst = 0, xtSrc = 0;
  if (doXt) {
    int rX = t / 9, kX = t - rX*9;
    xtDst = bidx(72 + kX, rX);
    xtSrc = rX*292 + kX;          // padded row stride 292 -> spreads banks
  }

  // ---------------- encoder: 8 -> 256 -> 256 -> 64 ----------------
  if (t < 32) { int r = t >> 3, k = t & 7; xS[k*4 + r] = x[brS[r]*8 + k]; }
  __syncthreads();

  float* z1S = gS;   // [n][4]
  if (t < 512) {
    int n = t >> 1, rh = (t & 1)*2;
    float acc[2];
    float b = eb1[n];
    acc[0]=b; acc[1]=b;
    #pragma unroll
    for (int k = 0; k < 8; ++k) { float w = eW1[n*8 + k]; FMA2(acc, w, &xS[k*4 + rh]); }
    #pragma unroll
    for (int j = 0; j < 2; ++j) z1S[n*4 + rh + j] = ftanh(acc[j]);
  }
  __syncthreads();
  float* z2S = rnnS; // [n][4]
  if (t < 512) {
    int n = t >> 1, rh = (t & 1)*2;
    float acc[2];
    float b = eb2[n];
    acc[0]=b; acc[1]=b;
    const float4* w4 = (const float4*)(eW2 + n*256);
    #pragma unroll 4
    for (int k4 = 0; k4 < 64; ++k4) {
      float4 w = w4[k4];
      FMA2(acc, w.x, &z1S[(4*k4+0)*4 + rh]);
      FMA2(acc, w.y, &z1S[(4*k4+1)*4 + rh]);
      FMA2(acc, w.z, &z1S[(4*k4+2)*4 + rh]);
      FMA2(acc, w.w, &z1S[(4*k4+3)*4 + rh]);
    }
    #pragma unroll
    for (int j = 0; j < 2; ++j) z2S[n*4 + rh + j] = ftanh(acc[j]);
  }
  __syncthreads();
  if (t < 128) {                       // h0 (linear) -> fragment k = 8+o, buffer 0
    int o = t >> 1, rh = (t & 1)*2;
    float acc[2];
    float b = eb3[o];
    acc[0]=b; acc[1]=b;
    const float4* w4 = (const float4*)(eW3 + o*256);
    #pragma unroll 4
    for (int k4 = 0; k4 < 64; ++k4) {
      float4 w = w4[k4];
      FMA2(acc, w.x, &z2S[(4*k4+0)*4 + rh]);
      FMA2(acc, w.y, &z2S[(4*k4+1)*4 + rh]);
      FMA2(acc, w.z, &z2S[(4*k4+2)*4 + rh]);
      FMA2(acc, w.w, &z2S[(4*k4+3)*4 + rh]);
    }
    #pragma unroll
    for (int j = 0; j < 2; ++j) hF[0][bidx(8 + o, rh + j)] = f2h(acc[j]);
  } else if (t < 160) {                // x part -> k = 0..7, buffer 0
    int tt2 = t - 128; int r = tt2 >> 3, k = tt2 & 7;
    hF[0][bidx(k, r)] = f2h(xS[k*4 + r]);
  }

  // ---------------- weights as fp16 A-fragments (gate-permuted rows) ----------------
  // n' = 4*unit + gate ; src row = gate*72 + unit. A[row=n'][k], k = kt*32+q_a*8+j.
  half8 Af[2][3];
  f32x4 biasq[2];
  #pragma unroll
  for (int i = 0; i < 2; ++i) {
    int u = 4*(2*wv + i) + q_a;
    biasq[i].x = b_ih[u]       + b_hh[u];
    biasq[i].y = b_ih[72 + u]  + b_hh[72 + u];
    biasq[i].z = b_ih[144 + u] + b_hh[144 + u];
    biasq[i].w = b_ih[216 + u] + b_hh[216 + u];
    int nprime = (2*wv + i)*16 + col;
    int srcrow = (nprime & 3)*72 + (nprime >> 2);
    #pragma unroll
    for (int kt = 0; kt < 3; ++kt) {
      union { unsigned short u16[8]; half8 h; } cw;
      #pragma unroll
      for (int j = 0; j < 8; ++j) {
        int k = kt*32 + q_a*8 + j;
        float v = 0.f;
        if (k < 72)      v = W_hh[srcrow*HH + k];
        else if (k < 81) v = W_ih[srcrow*9 + (k - 72)];
        cw.u16[j] = f2h(v);
      }
      Af[i][kt] = cw.h;
    }
  }

  // ---------------- LSTM over time: one barrier per step ----------------
#define MFMA16(A, B, C) __builtin_amdgcn_mfma_f32_16x16x32_f16(A, B, C, 0, 0, 0)
#define STEP(PAR) { \
    const unsigned short* hb = &hF[PAR][0]; \
    unsigned short* hn = &hF[(PAR) ^ 1][0]; \
    half8 bf0 = *(const half8*)(hb + bOff0); \
    half8 bf1 = *(const half8*)(hb + bOff1); \
    half8 bf2 = *(const half8*)(hb + bOff2); \
    f32x4 a0 = MFMA16(Af[0][0], bf0, biasq[0]); \
    f32x4 a1 = MFMA16(Af[1][0], bf0, biasq[1]); \
    a0 = MFMA16(Af[0][1], bf1, a0);  a1 = MFMA16(Af[1][1], bf1, a1); \
    a0 = MFMA16(Af[0][2], bf2, a0);  a1 = MFMA16(Af[1][2], bf2, a1); \
    float ig = gHi ? a1.x : a0.x, fg = gHi ? a1.y : a0.y; \
    float gg = gHi ? a1.z : a0.z, og = gHi ? a1.w : a0.w; \
    float hv = cellUpd(ig, fg, gg, og, cstA); \
    hn[ibA] = f2h(hv); \
    hvP = (step == cidxm1) ? hv : hvP; \
    hvC = (step == cidxE)  ? hv : hvC; \
    if (doXt && tc < 31) hn[xtDst] = f2h(rnnS[xtSrc + (tc + 1)*9]); \
    __syncthreads(); \
    ++tc; ++step; }

  int step = 0;
  for (int chunk = 0; chunk*32 <= maxIdx; ++chunk) {
    __syncthreads();                           // prior chunk / encoder reads of rnnS done
    if (doPf) *(float4*)&rnnS[pfR*292 + pfP*4] = pf;   // commit prefetched chunk
    if (doPf && (chunk + 1)*32 <= maxIdx) pf = rnnRow[(chunk + 1)*72];  // issue next early
    __syncthreads();
    if (doXt) hF[0][xtDst] = f2h(rnnS[xtSrc]); // xt for first step of chunk (par==0)
    __syncthreads();
    const int lim = min(31, maxIdx - chunk*32);
    int tc = 0;
    while (tc + 1 <= lim) { STEP(0) STEP(1) }
    if (tc <= lim) { STEP(0) }                 // odd tail only on the last chunk
  }
#undef STEP
#undef MFMA16

  // flush snapshots (lanes col and col+4 duplicate the same (unit,row): benign)
  snapP[cL][uA] = hvP;  snapC[cL][uA] = hvC;
  if (t < NR) dS[t] = deltas[brS[t]*TT + idxS[t]];
  __syncthreads();

  // ---------------- decoder: 72 -> 288 -> 288 -> 8 ----------------
  if (t < HH*NR) {                    // build dec_in into hS[u][r]
    int u = t >> 2, r = t & 3;
    float d = dS[r];
    float sp = snapP[r][u], sc = snapC[r][u];
    hS[u*4 + r] = fmaf(d, sc - sp, sp);
  }
  __syncthreads();

  // layer1: 288 x 72
  float* d1S = rnnS; // [n][4]
  {
    int n = t >> 1, rh = (t & 1)*2;
    float acc[2];
    float b = db1[n];
    acc[0]=b; acc[1]=b;
    const float4* w4 = (const float4*)(dW1 + n*HH);
    #pragma unroll 2
    for (int k4 = 0; k4 < 18; ++k4) {
      float4 w = w4[k4];
      FMA2(acc, w.x, &hS[(4*k4+0)*4 + rh]);
      FMA2(acc, w.y, &hS[(4*k4+1)*4 + rh]);
      FMA2(acc, w.z, &hS[(4*k4+2)*4 + rh]);
      FMA2(acc, w.w, &hS[(4*k4+3)*4 + rh]);
    }
    #pragma unroll
    for (int j = 0; j < 2; ++j) d1S[n*4 + rh + j] = ftanh(acc[j]);
  }
  __syncthreads();

  // layer2: 288 x 288
  float* d2S = gS;   // [n][4]
  {
    int n = t >> 1, rh = (t & 1)*2;
    float acc[2];
    float b = db2[n];
    acc[0]=b; acc[1]=b;
    const float4* w4 = (const float4*)(dW2 + n*288);
    #pragma unroll 4
    for (int k4 = 0; k4 < 72; ++k4) {
      float4 w = w4[k4];
      FMA2(acc, w.x, &d1S[(4*k4+0)*4 + rh]);
      FMA2(acc, w.y, &d1S[(4*k4+1)*4 + rh]);
      FMA2(acc, w.z, &d1S[(4*k4+2)*4 + rh]);
      FMA2(acc, w.w, &d1S[(4*k4+3)*4 + rh]);
    }
    #pragma unroll
    for (int j = 0; j < 2; ++j) d2S[n*4 + rh + j] = ftanh(acc[j]);
  }
  __syncthreads();

  // layer3: 8 x 288 (linear) + scatter store
  if (t < 32) {
    int o = t & 7, r = t >> 3;
    float acc3 = db3[o];
    const float* wr = dW3 + o*288;
    #pragma unroll 4
    for (int k = 0; k < 288; ++k) acc3 = fmaf(wr[k], d2S[k*4 + r], acc3);
    out[brS[r]*8 + o] = acc3;
  }
}

extern "C" void kernel_launch(void* const* d_in, const int* in_sizes, int n_in,
                              void* d_out, int out_size, void* d_ws, size_t ws_size,
                              hipStream_t stream) {
  const float* x      = (const float*)d_in[0];
  const float* rnn    = (const float*)d_in[1];
  const float* deltas = (const float*)d_in[2];
  const int*   h_lens = (const int*)  d_in[3];
  const float* W_ih   = (const float*)d_in[4];
  const float* W_hh   = (const float*)d_in[5];
  const float* b_ih   = (const float*)d_in[6];
  const float* b_hh   = (const float*)d_in[7];
  const float* eW1    = (const float*)d_in[8];
  const float* eb1    = (const float*)d_in[9];
  const float* eW2    = (const float*)d_in[10];
  const float* eb2    = (const float*)d_in[11];
  const float* eW3    = (const float*)d_in[12];
  const float* eb3    = (const float*)d_in[13];
  const float* dW1    = (const float*)d_in[14];
  const float* db1    = (const float*)d_in[15];
  const float* dW2    = (const float*)d_in[16];
  const float* db2    = (const float*)d_in[17];
  const float* dW3    = (const float*)d_in[18];
  const float* db3    = (const float*)d_in[19];
  float* out = (float*)d_out;

  int* perm = nullptr;
  if (ws_size >= 2048 * sizeof(int)) {
    perm = (int*)d_ws;
    cfm_sort<<<1, 256, 0, stream>>>(h_lens, perm);
  }
  cfm_main<<<NBLK, NTH, 0, stream>>>(x, rnn, deltas, h_lens, W_ih, W_hh, b_ih, b_hh,
                                     eW1, eb1, eW2, eb2, eW3, eb3,
                                     dW1, db1, dW2, db2, dW3, db3,
                                     perm, out);
}

// Round 5
// 443.827 us; speedup vs baseline: 1.2937x; 1.2937x over previous
//
#include <hip/hip_runtime.h>
#include <cstdint>

#define HH 72
#define NR 16          // 16 real batch rows per block = 16 real MFMA B-columns
#define NTH 576        // 9 waves x 2 tiles
#define NBLK 128
#define TT 512

typedef __attribute__((ext_vector_type(8))) _Float16 half8;
typedef __attribute__((ext_vector_type(4))) float f32x4;

#if __has_builtin(__builtin_amdgcn_exp2f)
#define EXP2(x) __builtin_amdgcn_exp2f(x)
#else
#define EXP2(x) exp2f(x)
#endif
#if __has_builtin(__builtin_amdgcn_rcpf)
#define RCP(x) __builtin_amdgcn_rcpf(x)
#else
#define RCP(x) (1.0f/(x))
#endif

__device__ __forceinline__ float fsig(float x) {
  float e = EXP2(x * -1.442695040888963f);
  return RCP(1.0f + e);
}
__device__ __forceinline__ float ftanh(float x) {
  float e = EXP2(x * -2.885390081777927f);
  return fmaf(2.0f, RCP(1.0f + e), -1.0f);
}

// fp32 -> fp16 bits (RNE via v_cvt_f16_f32)
__device__ __forceinline__ unsigned short f2h(float v) {
  union { _Float16 h; unsigned short u; } cv;
  cv.h = (_Float16)v;
  return cv.u;
}

// fragment ushort index for contraction-dim k, batch col m (0..15).
// Layout [kt*4+q][m=16][8]: 8 contiguous fp16 -> one ds_read_b128 per (group,m).
__device__ __forceinline__ int bidx(int k, int m) {
  return ((k >> 5)*4 + ((k >> 3) & 3))*128 + m*8 + (k & 7);
}

__device__ __forceinline__ float cellUpd(float ig, float fg, float gg, float og, float& c) {
  c = fmaf(fsig(fg), c, fsig(ig)*ftanh(gg));
  return fsig(og)*ftanh(c);
}

// accumulate 8 rows: A[j] += W_ * P_[j]
#define FMA8(A, W_, P_) { \
  const float4 _fa = *(const float4*)(P_); \
  const float4 _fb = *(const float4*)((P_) + 4); \
  A[0] = fmaf((W_), _fa.x, A[0]); A[1] = fmaf((W_), _fa.y, A[1]); \
  A[2] = fmaf((W_), _fa.z, A[2]); A[3] = fmaf((W_), _fa.w, A[3]); \
  A[4] = fmaf((W_), _fb.x, A[4]); A[5] = fmaf((W_), _fb.y, A[5]); \
  A[6] = fmaf((W_), _fb.z, A[6]); A[7] = fmaf((W_), _fb.w, A[7]); }

// counting sort of rows by h_lens (ascending) -> blocks get similar-length rows
__global__ void cfm_sort(const int* __restrict__ h_lens, int* __restrict__ perm) {
  __shared__ int hist[257];
  __shared__ int offs[257];
  const int t = threadIdx.x; // 256
  for (int i = t; i < 257; i += 256) hist[i] = 0;
  __syncthreads();
  for (int i = t; i < 2048; i += 256) {
    int bkt = min(max(h_lens[i] - 256, 0), 256);
    atomicAdd(&hist[bkt], 1);
  }
  __syncthreads();
  if (t == 0) { int s = 0; for (int i = 0; i < 257; ++i) { offs[i] = s; s += hist[i]; } }
  __syncthreads();
  for (int i = t; i < 2048; i += 256) {
    int bkt = min(max(h_lens[i] - 256, 0), 256);
    int pos = atomicAdd(&offs[bkt], 1);
    perm[pos] = i;
  }
}

// 16 rows/block, 128 blocks. 9 waves x 2 tiles; 16 REAL B-columns (no broadcast
// duplication): each lane owns one cell per tile with gates directly in acc.x..w.
__global__ __launch_bounds__(NTH, 2)
void cfm_main(const float* __restrict__ x, const float* __restrict__ rnn,
              const float* __restrict__ deltas, const int* __restrict__ h_lens,
              const float* __restrict__ W_ih, const float* __restrict__ W_hh,
              const float* __restrict__ b_ih, const float* __restrict__ b_hh,
              const float* __restrict__ eW1, const float* __restrict__ eb1,
              const float* __restrict__ eW2, const float* __restrict__ eb2,
              const float* __restrict__ eW3, const float* __restrict__ eb3,
              const float* __restrict__ dW1, const float* __restrict__ db1,
              const float* __restrict__ dW2, const float* __restrict__ db2,
              const float* __restrict__ dW3, const float* __restrict__ db3,
              const int* __restrict__ perm, float* __restrict__ out)
{
  __shared__ __align__(16) unsigned short hF[2][1536]; // fp16 [h|xt|pad] B-frags, dbuf
  __shared__ __align__(16) float gS[4608];             // enc z1S / dec d2S  [n][16]
  __shared__ __align__(16) float rnnS[16*292];         // rnn chunk [16][292]; enc z2S / dec d1S
  __shared__ __align__(16) float snapP[NR][HH];
  __shared__ __align__(16) float snapC[NR][HH];
  __shared__ __align__(16) float hS[HH*16];            // decoder dec_in [u][r]
  __shared__ __align__(16) float xS[8*16];             // [k][r]
  __shared__ int brS[NR];
  __shared__ int idxS[NR];
  __shared__ float dS[NR];

  const int t  = threadIdx.x;
  const int bb = blockIdx.x;

  for (int i = t; i < 1536; i += NTH) ((unsigned*)hF)[i] = 0;  // zero both buffers (pads!)

  if (t < NR) {
    int row = perm ? perm[bb*NR + t] : (bb*NR + t);
    brS[t]  = row;
    idxS[t] = h_lens[row] - 1;   // in [255, 511]
  }
  __syncthreads();

  int maxIdx = idxS[0];
  #pragma unroll
  for (int r = 1; r < NR; ++r) maxIdx = max(maxIdx, idxS[r]);

  const int lane = t & 63;
  const int wv   = t >> 6;                 // 0..8, tiles {2wv, 2wv+1}
  const int col  = lane & 15;              // REAL batch row
  const int q_a  = lane >> 4;
  const int uA0  = 4*(2*wv + 0) + q_a;     // cell 0: unit, batch=col
  const int uA1  = 4*(2*wv + 1) + q_a;     // cell 1
  const int ib0  = bidx(uA0, col);
  const int ib1  = bidx(uA1, col);
  const int cidxE  = idxS[col];
  const int cidxm1 = cidxE - 1;
  const int bOff0 = (0*4 + q_a)*128 + col*8;
  const int bOff1 = (1*4 + q_a)*128 + col*8;
  const int bOff2 = (2*4 + q_a)*128 + col*8;
  float cst0 = 0.f, cst1 = 0.f;
  float hvP0 = 0.f, hvC0 = 0.f, hvP1 = 0.f, hvC1 = 0.f;

  // prefetch rnn chunk 0 into regs (2 float4/thread: 1152 float4 = 16 rows * 288)
  const int pfR = t / 72;                  // 0..7
  const int pfP = t - pfR*72;              // 0..71
  const float4* rnnRowA = (const float4*)(rnn + (size_t)brS[pfR]*4608) + pfP;
  const float4* rnnRowB = (const float4*)(rnn + (size_t)brS[pfR + 8]*4608) + pfP;
  float4 pfA = rnnRowA[0];
  float4 pfB = rnnRowB[0];

  // xt staging: 144 values/step (16 rows x 9 k), on waves 5..7 (the 2-wave SIMDs,
  // keeping the 3-wave straggler SIMD free of side jobs)
  const bool doXt = (t >= 320) && (t < 464);
  int xtDst = 0, xtSrc = 0;
  if (doXt) {
    int e = t - 320;
    int rX = e / 9, kX = e - rX*9;         // rX 0..15
    xtDst = bidx(72 + kX, rX);
    xtSrc = rX*292 + kX;                   // padded row stride 292
  }

  // ---------------- encoder: 8 -> 256 -> 256 -> 64 (16 rows) ----------------
  if (t < 128) { int r = t >> 3, k = t & 7; xS[k*16 + r] = x[brS[r]*8 + k]; }
  __syncthreads();

  float* z1S = gS;   // [n][16]
  if (t < 512) {
    int n = t >> 1, rh = (t & 1)*8;
    float acc[8];
    float b = eb1[n];
    #pragma unroll
    for (int j = 0; j < 8; ++j) acc[j] = b;
    #pragma unroll
    for (int k = 0; k < 8; ++k) { float w = eW1[n*8 + k]; FMA8(acc, w, &xS[k*16 + rh]); }
    #pragma unroll
    for (int j = 0; j < 8; ++j) z1S[n*16 + rh + j] = ftanh(acc[j]);
  }
  __syncthreads();
  float* z2S = rnnS; // [n][16]
  if (t < 512) {
    int n = t >> 1, rh = (t & 1)*8;
    float acc[8];
    float b = eb2[n];
    #pragma unroll
    for (int j = 0; j < 8; ++j) acc[j] = b;
    const float4* w4 = (const float4*)(eW2 + n*256);
    #pragma unroll 2
    for (int k4 = 0; k4 < 64; ++k4) {
      float4 w = w4[k4];
      FMA8(acc, w.x, &z1S[(4*k4+0)*16 + rh]);
      FMA8(acc, w.y, &z1S[(4*k4+1)*16 + rh]);
      FMA8(acc, w.z, &z1S[(4*k4+2)*16 + rh]);
      FMA8(acc, w.w, &z1S[(4*k4+3)*16 + rh]);
    }
    #pragma unroll
    for (int j = 0; j < 8; ++j) z2S[n*16 + rh + j] = ftanh(acc[j]);
  }
  __syncthreads();
  if (t < 128) {                       // h0 (linear) -> fragment k = 8+o, buffer 0
    int o = t >> 1, rh = (t & 1)*8;
    float acc[8];
    float b = eb3[o];
    #pragma unroll
    for (int j = 0; j < 8; ++j) acc[j] = b;
    const float4* w4 = (const float4*)(eW3 + o*256);
    #pragma unroll 2
    for (int k4 = 0; k4 < 64; ++k4) {
      float4 w = w4[k4];
      FMA8(acc, w.x, &z2S[(4*k4+0)*16 + rh]);
      FMA8(acc, w.y, &z2S[(4*k4+1)*16 + rh]);
      FMA8(acc, w.z, &z2S[(4*k4+2)*16 + rh]);
      FMA8(acc, w.w, &z2S[(4*k4+3)*16 + rh]);
    }
    #pragma unroll
    for (int j = 0; j < 8; ++j) hF[0][bidx(8 + o, rh + j)] = f2h(acc[j]);
  } else if (t < 256) {                // x part -> k = 0..7, buffer 0
    int tt2 = t - 128; int r = tt2 >> 3, k = tt2 & 7;
    hF[0][bidx(k, r)] = f2h(xS[k*16 + r]);
  }

  // ---------------- weights as fp16 A-fragments (gate-permuted rows) ----------------
  // n' = 4*unit + gate ; src row = gate*72 + unit. A[row=n'][k], k = kt*32+q_a*8+j.
  half8 Af[2][3];
  f32x4 biasq[2];
  #pragma unroll
  for (int i = 0; i < 2; ++i) {
    int u = 4*(2*wv + i) + q_a;
    biasq[i].x = b_ih[u]       + b_hh[u];
    biasq[i].y = b_ih[72 + u]  + b_hh[72 + u];
    biasq[i].z = b_ih[144 + u] + b_hh[144 + u];
    biasq[i].w = b_ih[216 + u] + b_hh[216 + u];
    int nprime = (2*wv + i)*16 + col;
    int srcrow = (nprime & 3)*72 + (nprime >> 2);
    #pragma unroll
    for (int kt = 0; kt < 3; ++kt) {
      union { unsigned short u16[8]; half8 h; } cw;
      #pragma unroll
      for (int j = 0; j < 8; ++j) {
        int k = kt*32 + q_a*8 + j;
        float v = 0.f;
        if (k < 72)      v = W_hh[srcrow*HH + k];
        else if (k < 81) v = W_ih[srcrow*9 + (k - 72)];
        cw.u16[j] = f2h(v);
      }
      Af[i][kt] = cw.h;
    }
  }

  // ---------------- LSTM over time: one barrier per step ----------------
#define MFMA16(A, B, C) __builtin_amdgcn_mfma_f32_16x16x32_f16(A, B, C, 0, 0, 0)
#define STEP(PAR) { \
    const unsigned short* hb = &hF[PAR][0]; \
    unsigned short* hn = &hF[(PAR) ^ 1][0]; \
    half8 bf0 = *(const half8*)(hb + bOff0); \
    half8 bf1 = *(const half8*)(hb + bOff1); \
    half8 bf2 = *(const half8*)(hb + bOff2); \
    f32x4 a0 = MFMA16(Af[0][0], bf0, biasq[0]); \
    f32x4 a1 = MFMA16(Af[1][0], bf0, biasq[1]); \
    a0 = MFMA16(Af[0][1], bf1, a0);  a1 = MFMA16(Af[1][1], bf1, a1); \
    a0 = MFMA16(Af[0][2], bf2, a0);  a1 = MFMA16(Af[1][2], bf2, a1); \
    float hv0 = cellUpd(a0.x, a0.y, a0.z, a0.w, cst0); \
    float hv1 = cellUpd(a1.x, a1.y, a1.z, a1.w, cst1); \
    hn[ib0] = f2h(hv0); \
    hn[ib1] = f2h(hv1); \
    hvP0 = (step == cidxm1) ? hv0 : hvP0;  hvC0 = (step == cidxE) ? hv0 : hvC0; \
    hvP1 = (step == cidxm1) ? hv1 : hvP1;  hvC1 = (step == cidxE) ? hv1 : hvC1; \
    if (doXt && tc < 31) hn[xtDst] = f2h(rnnS[xtSrc + (tc + 1)*9]); \
    __syncthreads(); \
    ++tc; ++step; }

  int step = 0;
  for (int chunk = 0; chunk*32 <= maxIdx; ++chunk) {
    __syncthreads();                             // prior chunk / encoder reads of rnnS done
    *(float4*)&rnnS[pfR*292 + pfP*4] = pfA;      // commit prefetched chunk (rows 0-7)
    *(float4*)&rnnS[(pfR + 8)*292 + pfP*4] = pfB;  // rows 8-15
    if ((chunk + 1)*32 <= maxIdx) {              // issue next early
      pfA = rnnRowA[(chunk + 1)*72];
      pfB = rnnRowB[(chunk + 1)*72];
    }
    __syncthreads();
    if (doXt) hF[0][xtDst] = f2h(rnnS[xtSrc]);   // xt for first step of chunk (par==0)
    __syncthreads();
    const int lim = min(31, maxIdx - chunk*32);
    int tc = 0;
    while (tc + 1 <= lim) { STEP(0) STEP(1) }
    if (tc <= lim) { STEP(0) }                   // odd tail only on the last chunk
  }
#undef STEP
#undef MFMA16

  // flush snapshots (each lane owns 2 distinct (unit,row) cells)
  snapP[col][uA0] = hvP0;  snapC[col][uA0] = hvC0;
  snapP[col][uA1] = hvP1;  snapC[col][uA1] = hvC1;
  if (t < NR) dS[t] = deltas[brS[t]*TT + idxS[t]];
  __syncthreads();

  // ---------------- decoder: 72 -> 288 -> 288 -> 8 (16 rows) ----------------
  for (int p = t; p < HH*16; p += NTH) {   // build dec_in into hS[u][r]
    int u = p >> 4, r = p & 15;
    float d = dS[r];
    float sp = snapP[r][u], sc = snapC[r][u];
    hS[u*16 + r] = fmaf(d, sc - sp, sp);
  }
  __syncthreads();

  // layer1: 288 x 72
  float* d1S = rnnS; // [n][16]
  {
    int n = t >> 1, rh = (t & 1)*8;
    float acc[8];
    float b = db1[n];
    #pragma unroll
    for (int j = 0; j < 8; ++j) acc[j] = b;
    const float4* w4 = (const float4*)(dW1 + n*HH);
    #pragma unroll 2
    for (int k4 = 0; k4 < 18; ++k4) {
      float4 w = w4[k4];
      FMA8(acc, w.x, &hS[(4*k4+0)*16 + rh]);
      FMA8(acc, w.y, &hS[(4*k4+1)*16 + rh]);
      FMA8(acc, w.z, &hS[(4*k4+2)*16 + rh]);
      FMA8(acc, w.w, &hS[(4*k4+3)*16 + rh]);
    }
    #pragma unroll
    for (int j = 0; j < 8; ++j) d1S[n*16 + rh + j] = ftanh(acc[j]);
  }
  __syncthreads();

  // layer2: 288 x 288
  float* d2S = gS;   // [n][16]
  {
    int n = t >> 1, rh = (t & 1)*8;
    float acc[8];
    float b = db2[n];
    #pragma unroll
    for (int j = 0; j < 8; ++j) acc[j] = b;
    const float4* w4 = (const float4*)(dW2 + n*288);
    #pragma unroll 2
    for (int k4 = 0; k4 < 72; ++k4) {
      float4 w = w4[k4];
      FMA8(acc, w.x, &d1S[(4*k4+0)*16 + rh]);
      FMA8(acc, w.y, &d1S[(4*k4+1)*16 + rh]);
      FMA8(acc, w.z, &d1S[(4*k4+2)*16 + rh]);
      FMA8(acc, w.w, &d1S[(4*k4+3)*16 + rh]);
    }
    #pragma unroll
    for (int j = 0; j < 8; ++j) d2S[n*16 + rh + j] = ftanh(acc[j]);
  }
  __syncthreads();

  // layer3: 8 x 288 (linear) + scatter store
  if (t < 128) {
    int o = t & 7, r = t >> 3;
    float acc3 = db3[o];
    const float* wr = dW3 + o*288;
    #pragma unroll 4
    for (int k = 0; k < 288; ++k) acc3 = fmaf(wr[k], d2S[k*16 + r], acc3);
    out[brS[r]*8 + o] = acc3;
  }
}

extern "C" void kernel_launch(void* const* d_in, const int* in_sizes, int n_in,
                              void* d_out, int out_size, void* d_ws, size_t ws_size,
                              hipStream_t stream) {
  const float* x      = (const float*)d_in[0];
  const float* rnn    = (const float*)d_in[1];
  const float* deltas = (const float*)d_in[2];
  const int*   h_lens = (const int*)  d_in[3];
  const float* W_ih   = (const float*)d_in[4];
  const float* W_hh   = (const float*)d_in[5];
  const float* b_ih   = (const float*)d_in[6];
  const float* b_hh   = (const float*)d_in[7];
  const float* eW1    = (const float*)d_in[8];
  const float* eb1    = (const float*)d_in[9];
  const float* eW2    = (const float*)d_in[10];
  const float* eb2    = (const float*)d_in[11];
  const float* eW3    = (const float*)d_in[12];
  const float* eb3    = (const float*)d_in[13];
  const float* dW1    = (const float*)d_in[14];
  const float* db1    = (const float*)d_in[15];
  const float* dW2    = (const float*)d_in[16];
  const float* db2    = (const float*)d_in[17];
  const float* dW3    = (const float*)d_in[18];
  const float* db3    = (const float*)d_in[19];
  float* out = (float*)d_out;

  int* perm = nullptr;
  if (ws_size >= 2048 * sizeof(int)) {
    perm = (int*)d_ws;
    cfm_sort<<<1, 256, 0, stream>>>(h_lens, perm);
  }
  cfm_main<<<NBLK, NTH, 0, stream>>>(x, rnn, deltas, h_lens, W_ih, W_hh, b_ih, b_hh,
                                     eW1, eb1, eW2, eb2, eW3, eb3,
                                     dW1, db1, dW2, db2, dW3, db3,
                                     perm, out);
}

// Round 6
// 399.657 us; speedup vs baseline: 1.4367x; 1.1105x over previous
//
#include <hip/hip_runtime.h>
#include <cstdint>

#define HH 72
#define NR 8
#define NTH 576        // 9 waves x 2 tiles (R1 structure)
#define NBLK 256
#define TT 512

typedef __attribute__((ext_vector_type(8))) _Float16 half8;
typedef __attribute__((ext_vector_type(4))) float f32x4;

#if __has_builtin(__builtin_amdgcn_exp2f)
#define EXP2(x) __builtin_amdgcn_exp2f(x)
#else
#define EXP2(x) exp2f(x)
#endif
#if __has_builtin(__builtin_amdgcn_rcpf)
#define RCP(x) __builtin_amdgcn_rcpf(x)
#else
#define RCP(x) (1.0f/(x))
#endif

// lgkm-only barrier: LDS visibility without draining vmcnt (global prefetch
// stays in flight across step barriers). Producer writes drained by lgkmcnt(0).
#define BARL() asm volatile("s_waitcnt lgkmcnt(0)\n\ts_barrier" ::: "memory")

__device__ __forceinline__ float fsig(float x) {
  float e = EXP2(x * -1.442695040888963f);
  return RCP(1.0f + e);
}
__device__ __forceinline__ float ftanh(float x) {
  float e = EXP2(x * -2.885390081777927f);
  return fmaf(2.0f, RCP(1.0f + e), -1.0f);
}

// fp32 -> fp16 bits (RNE via v_cvt_f16_f32)
__device__ __forceinline__ unsigned short f2h(float v) {
  union { _Float16 h; unsigned short u; } cv;
  cv.h = (_Float16)v;
  return cv.u;
}

// fragment ushort index for contraction-dim k (<72), batch col m (0..7).
// Layout [kgrp][m=8][8]: 8 contiguous fp16 -> one ds_read_b128 per (group,m).
__device__ __forceinline__ int bidx(int k, int m) {
  return ((k >> 5)*4 + ((k >> 3) & 3))*64 + m*8 + (k & 7);
}

__device__ __forceinline__ float cellUpd(float ig, float fg, float gg, float og, float& c) {
  c = fmaf(fsig(fg), c, fsig(ig)*ftanh(gg));
  return fsig(og)*ftanh(c);
}

// accumulate 4 rows: A[r] += W_ * P_[r]
#define FMA4(A, W_, P_) { \
  const float4 _fa = *(const float4*)(P_); \
  A[0] = fmaf((W_), _fa.x, A[0]); A[1] = fmaf((W_), _fa.y, A[1]); \
  A[2] = fmaf((W_), _fa.z, A[2]); A[3] = fmaf((W_), _fa.w, A[3]); }

// counting sort of rows by h_lens (ascending) -> blocks get similar-length rows
__global__ void cfm_sort(const int* __restrict__ h_lens, int* __restrict__ perm) {
  __shared__ int hist[257];
  __shared__ int offs[257];
  const int t = threadIdx.x; // 256
  for (int i = t; i < 257; i += 256) hist[i] = 0;
  __syncthreads();
  for (int i = t; i < 2048; i += 256) {
    int bkt = min(max(h_lens[i] - 256, 0), 256);
    atomicAdd(&hist[bkt], 1);
  }
  __syncthreads();
  if (t == 0) { int s = 0; for (int i = 0; i < 257; ++i) { offs[i] = s; s += hist[i]; } }
  __syncthreads();
  for (int i = t; i < 2048; i += 256) {
    int bkt = min(max(h_lens[i] - 256, 0), 256);
    int pos = atomicAdd(&offs[bkt], 1);
    perm[pos] = i;
  }
}

// 8 rows/block, 256 blocks, 9 waves x 2 tiles, broadcast-8 B columns.
// xt pre-staged per chunk into hXT (read via per-lane kt2 addresses);
// step barriers are lgkm-only so the rnn prefetch never stalls a barrier.
__global__ __launch_bounds__(NTH, 2)
void cfm_main(const float* __restrict__ x, const float* __restrict__ rnn,
              const float* __restrict__ deltas, const int* __restrict__ h_lens,
              const float* __restrict__ W_ih, const float* __restrict__ W_hh,
              const float* __restrict__ b_ih, const float* __restrict__ b_hh,
              const float* __restrict__ eW1, const float* __restrict__ eb1,
              const float* __restrict__ eW2, const float* __restrict__ eb2,
              const float* __restrict__ eW3, const float* __restrict__ eb3,
              const float* __restrict__ dW1, const float* __restrict__ db1,
              const float* __restrict__ dW2, const float* __restrict__ db2,
              const float* __restrict__ dW3, const float* __restrict__ db3,
              const int* __restrict__ perm, float* __restrict__ out)
{
  __shared__ __align__(16) unsigned short hF[2][576];  // fp16 h B-frags (k 0..71), dbuf
  __shared__ __align__(16) unsigned short hXT[32*128]; // per-chunk xt frags [tc][2 grp][8 rows][8]
  __shared__ __align__(16) unsigned short zPadS[64];   // zero pad for q_a==3 kt2 reads
  __shared__ __align__(16) float gS[2304];             // enc z1S / dec d2S  [n][8]
  __shared__ __align__(16) float rnnS[2336];           // rnn chunk [8][292]; enc z2S / dec d1S
  __shared__ __align__(16) float snapP[NR][HH];
  __shared__ __align__(16) float snapC[NR][HH];
  __shared__ __align__(16) float hS[HH*NR];            // decoder dec_in [u][r]
  __shared__ __align__(16) float xS[8*NR];             // [k][r]
  __shared__ int brS[NR];
  __shared__ int idxS[NR];
  __shared__ float dS[NR];

  const int t  = threadIdx.x;
  const int bb = blockIdx.x;

  // zero hXT pad slots + zero pad block (once; staging rewrites real slots each chunk)
  for (int i = t; i < 2048; i += NTH) ((unsigned*)hXT)[i] = 0;
  if (t < 32) ((unsigned*)zPadS)[t] = 0;

  if (t < NR) {
    int row = perm ? perm[bb*NR + t] : (bb*NR + t);
    brS[t]  = row;
    idxS[t] = h_lens[row] - 1;   // in [255, 511]
  }
  __syncthreads();

  int maxIdx = idxS[0];
  #pragma unroll
  for (int r = 1; r < NR; ++r) maxIdx = max(maxIdx, idxS[r]);

  const int lane = t & 63;
  const int wv   = t >> 6;                 // 0..8, tiles {2wv, 2wv+1}
  const int col  = lane & 15;
  const int q_a  = lane >> 4;
  const int cL   = col & 7;                // batch col (cols 8-15 broadcast dups)
  const int gHi  = col >> 3;               // which of my wave's 2 tiles
  const int uA   = 4*(2*wv + gHi) + q_a;   // unit owned
  const int cidxE  = idxS[cL];
  const int cidxm1 = cidxE - 1;
  const int ibA  = bidx(uA, cL);
  const int c8   = cL*8;
  const int bOff0 = (0*4 + q_a)*64 + c8;   // kt0: k 0..31
  const int bOff1 = (1*4 + q_a)*64 + c8;   // kt1: k 32..63
  // kt2 (k 64..95): q_a==0 -> h tail (group 8 of hF), q_a==1/2 -> hXT[tc], q_a==3 -> pad
  const int midOff = (q_a - 1)*64 + c8;    // valid for q_a 1..2
  float cstA = 0.f;
  float hvP = 0.f, hvC = 0.f;

  // prefetch rnn chunk 0 into regs (1 float4/thread: 576*16B = 8 rows * 288 floats)
  const int pfR = t / 72;
  const int pfP = t - pfR*72;
  const float4* rnnRow = (const float4*)(rnn + (size_t)brS[pfR]*4608) + pfP;
  float4 pf = rnnRow[0];

  // ---------------- encoder: 8 -> 256 -> 256 -> 64 ----------------
  if (t < 64) { int r = t >> 3, k = t & 7; xS[k*8 + r] = x[brS[r]*8 + k]; }
  __syncthreads();

  float* z1S = gS;   // [n][8]
  if (t < 512) {
    int n = t >> 1, rh = (t & 1)*4;
    float acc[4];
    float b = eb1[n];
    acc[0]=b; acc[1]=b; acc[2]=b; acc[3]=b;
    #pragma unroll
    for (int k = 0; k < 8; ++k) { float w = eW1[n*8 + k]; FMA4(acc, w, &xS[k*8 + rh]); }
    #pragma unroll
    for (int j = 0; j < 4; ++j) z1S[n*8 + rh + j] = ftanh(acc[j]);
  }
  __syncthreads();
  float* z2S = rnnS; // [n][8]
  if (t < 512) {
    int n = t >> 1, rh = (t & 1)*4;
    float acc[4];
    float b = eb2[n];
    acc[0]=b; acc[1]=b; acc[2]=b; acc[3]=b;
    const float4* w4 = (const float4*)(eW2 + n*256);
    #pragma unroll 4
    for (int k4 = 0; k4 < 64; ++k4) {
      float4 w = w4[k4];
      FMA4(acc, w.x, &z1S[(4*k4+0)*8 + rh]);
      FMA4(acc, w.y, &z1S[(4*k4+1)*8 + rh]);
      FMA4(acc, w.z, &z1S[(4*k4+2)*8 + rh]);
      FMA4(acc, w.w, &z1S[(4*k4+3)*8 + rh]);
    }
    #pragma unroll
    for (int j = 0; j < 4; ++j) z2S[n*8 + rh + j] = ftanh(acc[j]);
  }
  __syncthreads();
  if (t < 128) {                       // h0 (linear) -> fragment k = 8+o, buffer 0
    int o = t >> 1, rh = (t & 1)*4;
    float acc[4];
    float b = eb3[o];
    acc[0]=b; acc[1]=b; acc[2]=b; acc[3]=b;
    const float4* w4 = (const float4*)(eW3 + o*256);
    #pragma unroll 4
    for (int k4 = 0; k4 < 64; ++k4) {
      float4 w = w4[k4];
      FMA4(acc, w.x, &z2S[(4*k4+0)*8 + rh]);
      FMA4(acc, w.y, &z2S[(4*k4+1)*8 + rh]);
      FMA4(acc, w.z, &z2S[(4*k4+2)*8 + rh]);
      FMA4(acc, w.w, &z2S[(4*k4+3)*8 + rh]);
    }
    #pragma unroll
    for (int j = 0; j < 4; ++j) hF[0][bidx(8 + o, rh + j)] = f2h(acc[j]);
  } else if (t < 192) {                // x part -> k = 0..7, buffer 0
    int tt2 = t - 128; int r = tt2 >> 3, k = tt2 & 7;
    hF[0][bidx(k, r)] = f2h(xS[k*8 + r]);
  }

  // ---------------- weights as fp16 A-fragments (gate-permuted rows) ----------------
  // n' = 4*unit + gate ; src row = gate*72 + unit. A[row=n'][k], k = kt*32+q_a*8+j.
  half8 Af[2][3];
  f32x4 biasq[2];
  #pragma unroll
  for (int i = 0; i < 2; ++i) {
    int u = 4*(2*wv + i) + q_a;
    biasq[i].x = b_ih[u]       + b_hh[u];
    biasq[i].y = b_ih[72 + u]  + b_hh[72 + u];
    biasq[i].z = b_ih[144 + u] + b_hh[144 + u];
    biasq[i].w = b_ih[216 + u] + b_hh[216 + u];
    int nprime = (2*wv + i)*16 + col;
    int srcrow = (nprime & 3)*72 + (nprime >> 2);
    #pragma unroll
    for (int kt = 0; kt < 3; ++kt) {
      union { unsigned short u16[8]; half8 h; } cw;
      #pragma unroll
      for (int j = 0; j < 8; ++j) {
        int k = kt*32 + q_a*8 + j;
        float v = 0.f;
        if (k < 72)      v = W_hh[srcrow*HH + k];
        else if (k < 81) v = W_ih[srcrow*9 + (k - 72)];
        cw.u16[j] = f2h(v);
      }
      Af[i][kt] = cw.h;
    }
  }

  // ---------------- LSTM over time: one lgkm barrier per step ----------------
#define MFMA16(A, B, C) __builtin_amdgcn_mfma_f32_16x16x32_f16(A, B, C, 0, 0, 0)
  const f32x4 zero4 = {0.f, 0.f, 0.f, 0.f};
#define STEP(PAR) { \
    const unsigned short* hb = &hF[PAR][0]; \
    unsigned short* hn = &hF[(PAR) ^ 1][0]; \
    const unsigned short* p2 = (q_a == 0) ? (hb + 512 + c8) \
                             : (q_a == 3) ? (&zPadS[0] + c8) \
                             : (&hXT[0] + tc*128 + midOff); \
    half8 bf0 = *(const half8*)(hb + bOff0); \
    half8 bf1 = *(const half8*)(hb + bOff1); \
    half8 bf2 = *(const half8*)p2; \
    f32x4 y0 = MFMA16(Af[0][1], bf1, zero4); \
    f32x4 y1 = MFMA16(Af[1][1], bf1, zero4); \
    f32x4 x0 = MFMA16(Af[0][0], bf0, biasq[0]); \
    f32x4 x1 = MFMA16(Af[1][0], bf0, biasq[1]); \
    x0 = MFMA16(Af[0][2], bf2, x0); \
    x1 = MFMA16(Af[1][2], bf2, x1); \
    f32x4 a0 = x0 + y0; \
    f32x4 a1 = x1 + y1; \
    float ig = gHi ? a1.x : a0.x, fg = gHi ? a1.y : a0.y; \
    float gg = gHi ? a1.z : a0.z, og = gHi ? a1.w : a0.w; \
    float hv = cellUpd(ig, fg, gg, og, cstA); \
    hn[ibA] = f2h(hv); \
    hvP = (step == cidxm1) ? hv : hvP; \
    hvC = (step == cidxE)  ? hv : hvC; \
    BARL(); \
    ++tc; ++step; }

  int step = 0;
  for (int chunk = 0; chunk*32 <= maxIdx; ++chunk) {
    BARL();                                    // prior readers of rnnS done
    *(float4*)&rnnS[pfR*292 + pfP*4] = pf;     // commit prefetched chunk
    if ((chunk + 1)*32 <= maxIdx) pf = rnnRow[(chunk + 1)*72];  // issue next early
    BARL();
    // stage this chunk's xt into hXT: 2304 values, 4 per thread.
    // dest: [tc][grp0: k72..79 -> r*8+kk | grp1: k80 -> 64 + r*8]
    for (int e = t; e < 2304; e += NTH) {
      int r = e / 288, rem = e - r*288;
      int tcs = rem / 9, kk = rem - tcs*9;
      float v = rnnS[r*292 + tcs*9 + kk];
      int dst = tcs*128 + ((kk < 8) ? (r*8 + kk) : (64 + r*8));
      hXT[dst] = f2h(v);
    }
    BARL();
    const int lim = min(31, maxIdx - chunk*32);
    int tc = 0;
    while (tc + 1 <= lim) { STEP(0) STEP(1) }
    if (tc <= lim) { STEP(0) }                 // odd tail only on the last chunk
  }
#undef STEP
#undef MFMA16

  // flush snapshots (each lane owns one distinct (unit,row) cell)
  snapP[cL][uA] = hvP;  snapC[cL][uA] = hvC;
  if (t < NR) dS[t] = deltas[brS[t]*TT + idxS[t]];
  __syncthreads();

  // ---------------- decoder: 72 -> 288 -> 288 -> 8 ----------------
  { // build dec_in into hS[u][r]  (576 elements, one per thread)
    int u = t % 72, r = t / 72;
    float d = dS[r];
    float sp = snapP[r][u], sc = snapC[r][u];
    hS[u*8 + r] = fmaf(d, sc - sp, sp);
  }
  __syncthreads();

  // layer1: 288 x 72  (all 576 threads: n = t>>1, half-row rh)
  float* d1S = rnnS; // [n][8]
  {
    int n = t >> 1, rh = (t & 1)*4;
    float acc[4];
    float b = db1[n];
    acc[0]=b; acc[1]=b; acc[2]=b; acc[3]=b;
    const float4* w4 = (const float4*)(dW1 + n*HH);
    #pragma unroll 2
    for (int k4 = 0; k4 < 18; ++k4) {
      float4 w = w4[k4];
      FMA4(acc, w.x, &hS[(4*k4+0)*8 + rh]);
      FMA4(acc, w.y, &hS[(4*k4+1)*8 + rh]);
      FMA4(acc, w.z, &hS[(4*k4+2)*8 + rh]);
      FMA4(acc, w.w, &hS[(4*k4+3)*8 + rh]);
    }
    #pragma unroll
    for (int j = 0; j < 4; ++j) d1S[n*8 + rh + j] = ftanh(acc[j]);
  }
  __syncthreads();

  // layer2: 288 x 288
  float* d2S = gS;   // [n][8]
  {
    int n = t >> 1, rh = (t & 1)*4;
    float acc[4];
    float b = db2[n];
    acc[0]=b; acc[1]=b; acc[2]=b; acc[3]=b;
    const float4* w4 = (const float4*)(dW2 + n*288);
    #pragma unroll 4
    for (int k4 = 0; k4 < 72; ++k4) {
      float4 w = w4[k4];
      FMA4(acc, w.x, &d1S[(4*k4+0)*8 + rh]);
      FMA4(acc, w.y, &d1S[(4*k4+1)*8 + rh]);
      FMA4(acc, w.z, &d1S[(4*k4+2)*8 + rh]);
      FMA4(acc, w.w, &d1S[(4*k4+3)*8 + rh]);
    }
    #pragma unroll
    for (int j = 0; j < 4; ++j) d2S[n*8 + rh + j] = ftanh(acc[j]);
  }
  __syncthreads();

  // layer3: 8 x 288 (linear) + scatter store
  if (t < 64) {
    int o = t & 7, r = t >> 3;
    float acc3 = db3[o];
    const float* wr = dW3 + o*288;
    #pragma unroll 4
    for (int k = 0; k < 288; ++k) acc3 = fmaf(wr[k], d2S[k*8 + r], acc3);
    out[brS[r]*8 + o] = acc3;
  }
}

extern "C" void kernel_launch(void* const* d_in, const int* in_sizes, int n_in,
                              void* d_out, int out_size, void* d_ws, size_t ws_size,
                              hipStream_t stream) {
  const float* x      = (const float*)d_in[0];
  const float* rnn    = (const float*)d_in[1];
  const float* deltas = (const float*)d_in[2];
  const int*   h_lens = (const int*)  d_in[3];
  const float* W_ih   = (const float*)d_in[4];
  const float* W_hh   = (const float*)d_in[5];
  const float* b_ih   = (const float*)d_in[6];
  const float* b_hh   = (const float*)d_in[7];
  const float* eW1    = (const float*)d_in[8];
  const float* eb1    = (const float*)d_in[9];
  const float* eW2    = (const float*)d_in[10];
  const float* eb2    = (const float*)d_in[11];
  const float* eW3    = (const float*)d_in[12];
  const float* eb3    = (const float*)d_in[13];
  const float* dW1    = (const float*)d_in[14];
  const float* db1    = (const float*)d_in[15];
  const float* dW2    = (const float*)d_in[16];
  const float* db2    = (const float*)d_in[17];
  const float* dW3    = (const float*)d_in[18];
  const float* db3    = (const float*)d_in[19];
  float* out = (float*)d_out;

  int* perm = nullptr;
  if (ws_size >= 2048 * sizeof(int)) {
    perm = (int*)d_ws;
    cfm_sort<<<1, 256, 0, stream>>>(h_lens, perm);
  }
  cfm_main<<<NBLK, NTH, 0, stream>>>(x, rnn, deltas, h_lens, W_ih, W_hh, b_ih, b_hh,
                                     eW1, eb1, eW2, eb2, eW3, eb3,
                                     dW1, db1, dW2, db2, dW3, db3,
                                     perm, out);
}

// Round 7
// 391.024 us; speedup vs baseline: 1.4684x; 1.0221x over previous
//
#include <hip/hip_runtime.h>
#include <cstdint>

#define HH 72
#define NR 8
#define NTH 576
#define NBLK 256
#define TT 512

typedef __attribute__((ext_vector_type(8))) _Float16 half8;
typedef __attribute__((ext_vector_type(4))) float f32x4;

#if __has_builtin(__builtin_amdgcn_exp2f)
#define EXP2(x) __builtin_amdgcn_exp2f(x)
#else
#define EXP2(x) exp2f(x)
#endif
#if __has_builtin(__builtin_amdgcn_rcpf)
#define RCP(x) __builtin_amdgcn_rcpf(x)
#else
#define RCP(x) (1.0f/(x))
#endif

// lgkm-only barrier: LDS visibility without draining vmcnt -> the rnn global
// prefetch stays in flight across barriers instead of stalling the first one.
#define BARL() asm volatile("s_waitcnt lgkmcnt(0)\n\ts_barrier" ::: "memory")

__device__ __forceinline__ float fsig(float x) {
  float e = EXP2(x * -1.442695040888963f);
  return RCP(1.0f + e);
}
__device__ __forceinline__ float ftanh(float x) {
  float e = EXP2(x * -2.885390081777927f);
  return fmaf(2.0f, RCP(1.0f + e), -1.0f);
}

// fp32 -> fp16 bits (RNE via v_cvt_f16_f32)
__device__ __forceinline__ unsigned short f2h(float v) {
  union { _Float16 h; unsigned short u; } cv;
  cv.h = (_Float16)v;
  return cv.u;
}

// fragment ushort index for contraction-dim k, batch col m (0..7).
// Layout [kt*4+q][m=8][8]: 8 contiguous fp16 -> one ds_read_b128 per (group,m).
__device__ __forceinline__ int bidx(int k, int m) {
  return ((k >> 5)*4 + ((k >> 3) & 3))*64 + m*8 + (k & 7);
}

__device__ __forceinline__ float cellUpd(float ig, float fg, float gg, float og, float& c) {
  c = fmaf(fsig(fg), c, fsig(ig)*ftanh(gg));
  return fsig(og)*ftanh(c);
}

// accumulate 4 rows: A[r] += W_ * P_[r]
#define FMA4(A, W_, P_) { \
  const float4 _fa = *(const float4*)(P_); \
  A[0] = fmaf((W_), _fa.x, A[0]); A[1] = fmaf((W_), _fa.y, A[1]); \
  A[2] = fmaf((W_), _fa.z, A[2]); A[3] = fmaf((W_), _fa.w, A[3]); }

// counting sort of rows by h_lens (ascending) -> blocks get similar-length rows
__global__ void cfm_sort(const int* __restrict__ h_lens, int* __restrict__ perm) {
  __shared__ int hist[257];
  __shared__ int offs[257];
  const int t = threadIdx.x; // 256
  for (int i = t; i < 257; i += 256) hist[i] = 0;
  __syncthreads();
  for (int i = t; i < 2048; i += 256) {
    int bkt = min(max(h_lens[i] - 256, 0), 256);
    atomicAdd(&hist[bkt], 1);
  }
  __syncthreads();
  if (t == 0) { int s = 0; for (int i = 0; i < 257; ++i) { offs[i] = s; s += hist[i]; } }
  __syncthreads();
  for (int i = t; i < 2048; i += 256) {
    int bkt = min(max(h_lens[i] - 256, 0), 256);
    int pos = atomicAdd(&offs[bkt], 1);
    perm[pos] = i;
  }
}

// NR=8 rows/block, 256 blocks, 9 waves x 2 tiles (the 269us R1 structure) plus
// four separable fixes: lgkm-only barriers, reg-latched snapshots, 2-deep MFMA
// chain, xt staging moved off the 3-wave straggler SIMD.
__global__ __launch_bounds__(NTH, 2)
void cfm_main(const float* __restrict__ x, const float* __restrict__ rnn,
              const float* __restrict__ deltas, const int* __restrict__ h_lens,
              const float* __restrict__ W_ih, const float* __restrict__ W_hh,
              const float* __restrict__ b_ih, const float* __restrict__ b_hh,
              const float* __restrict__ eW1, const float* __restrict__ eb1,
              const float* __restrict__ eW2, const float* __restrict__ eb2,
              const float* __restrict__ eW3, const float* __restrict__ eb3,
              const float* __restrict__ dW1, const float* __restrict__ db1,
              const float* __restrict__ dW2, const float* __restrict__ db2,
              const float* __restrict__ dW3, const float* __restrict__ db3,
              const int* __restrict__ perm, float* __restrict__ out)
{
  __shared__ __align__(16) unsigned short hF[2][768];  // fp16 [h|xt|pad] B-fragments, dbuf
  __shared__ __align__(16) float gS[2304];             // enc z1S / dec d2S  [n][8]
  __shared__ __align__(16) float rnnS[2336];           // rnn chunk; enc z2S / dec d1S
  __shared__ __align__(16) float snapP[NR][HH];
  __shared__ __align__(16) float snapC[NR][HH];
  __shared__ __align__(16) float hS[HH*NR];            // decoder dec_in [u][r]
  __shared__ __align__(16) float xS[8*NR];             // [k][r]
  __shared__ int brS[NR];
  __shared__ int idxS[NR];
  __shared__ float dS[NR];

  const int t  = threadIdx.x;
  const int bb = blockIdx.x;

  for (int i = t; i < 768; i += NTH) ((unsigned*)hF)[i] = 0;  // zero both buffers (pads!)

  if (t < NR) {
    int row = perm ? perm[bb*NR + t] : (bb*NR + t);
    brS[t]  = row;
    idxS[t] = h_lens[row] - 1;   // in [255, 511]
  }
  __syncthreads();

  int maxIdx = idxS[0];
  #pragma unroll
  for (int r = 1; r < NR; ++r) maxIdx = max(maxIdx, idxS[r]);

  const int lane = t & 63;
  const int wv   = t >> 6;                 // 0..8, tiles {2wv, 2wv+1}
  const int col  = lane & 15;
  const int q_a  = lane >> 4;
  const int cL   = col & 7;                // batch col
  const int gHi  = col >> 3;               // which of my wave's 2 tiles
  const int uA   = 4*(2*wv + gHi) + q_a;   // unit owned
  const int cidxE  = idxS[cL];
  const int cidxm1 = cidxE - 1;
  const int ibA  = bidx(uA, cL);
  const int bOff0 = (0*4 + q_a)*64 + cL*8; // broadcast read: col&7
  const int bOff1 = (1*4 + q_a)*64 + cL*8;
  const int bOff2 = (2*4 + q_a)*64 + cL*8;
  float cstA = 0.f;
  float hvP = 0.f, hvC = 0.f;              // reg-latched snapshots

  // prefetch rnn chunk 0 into regs (1 float4 per thread: 576*16B = 8 rows * 288 floats)
  const int pfR = t / 72;
  const int pfP = t - pfR*72;
  const float4* rnnRow = (const float4*)(rnn + (size_t)brS[pfR]*4608) + pfP;
  float4 pf = rnnRow[0];

  // xt staging lanes: 72 values/step (8 rows x 9 k) on waves 1..2 (SIMD1/2),
  // keeping the 3-wave SIMD0 free of side jobs.
  const bool doXt = (t >= 64) && (t < 136);
  int xtDst = 0, xtSrc = 0;
  if (doXt) {
    int e = t - 64;
    int rX = e / 9, kX = e - rX*9;
    xtDst = bidx(72 + kX, rX);
    xtSrc = rX*292 + kX;          // padded row stride 292 -> spreads banks
  }

  // ---------------- encoder: 8 -> 256 -> 256 -> 64 ----------------
  if (t < 64) { int r = t >> 3, k = t & 7; xS[k*8 + r] = x[brS[r]*8 + k]; }
  __syncthreads();

  float* z1S = gS;   // [n][8]
  if (t < 512) {
    int n = t >> 1, rh = (t & 1)*4;
    float acc[4];
    float b = eb1[n];
    acc[0]=b; acc[1]=b; acc[2]=b; acc[3]=b;
    #pragma unroll
    for (int k = 0; k < 8; ++k) { float w = eW1[n*8 + k]; FMA4(acc, w, &xS[k*8 + rh]); }
    #pragma unroll
    for (int j = 0; j < 4; ++j) z1S[n*4 + rh + j - (rh ? 4 : 0) + (rh ? 4 : 0)] = ftanh(acc[j]);  // z1S[n*8? see below]
  }
  __syncthreads();
  // NOTE: fix indexing uniformly (z1S layout [n][8])
  // (the line above writes z1S[n*4 + ...]: correct form below)
  if (t < 512) {
    int n = t >> 1, rh = (t & 1)*4;
    // recompute to guarantee layout [n][8] (cheap: 8 FMAs)
    float acc[4];
    float b = eb1[n];
    acc[0]=b; acc[1]=b; acc[2]=b; acc[3]=b;
    #pragma unroll
    for (int k = 0; k < 8; ++k) { float w = eW1[n*8 + k]; FMA4(acc, w, &xS[k*8 + rh]); }
    #pragma unroll
    for (int j = 0; j < 4; ++j) z1S[n*8 + rh + j] = ftanh(acc[j]);
  }
  __syncthreads();
  float* z2S = rnnS; // [n][8]
  if (t < 512) {
    int n = t >> 1, rh = (t & 1)*4;
    float acc[4];
    float b = eb2[n];
    acc[0]=b; acc[1]=b; acc[2]=b; acc[3]=b;
    const float4* w4 = (const float4*)(eW2 + n*256);
    #pragma unroll 4
    for (int k4 = 0; k4 < 64; ++k4) {
      float4 w = w4[k4];
      FMA4(acc, w.x, &z1S[(4*k4+0)*8 + rh]);
      FMA4(acc, w.y, &z1S[(4*k4+1)*8 + rh]);
      FMA4(acc, w.z, &z1S[(4*k4+2)*8 + rh]);
      FMA4(acc, w.w, &z1S[(4*k4+3)*8 + rh]);
    }
    #pragma unroll
    for (int j = 0; j < 4; ++j) z2S[n*8 + rh + j] = ftanh(acc[j]);
  }
  __syncthreads();
  if (t < 128) {                       // h0 (linear) -> fragment k = 8+o, buffer 0
    int o = t >> 1, rh = (t & 1)*4;
    float acc[4];
    float b = eb3[o];
    acc[0]=b; acc[1]=b; acc[2]=b; acc[3]=b;
    const float4* w4 = (const float4*)(eW3 + o*256);
    #pragma unroll 4
    for (int k4 = 0; k4 < 64; ++k4) {
      float4 w = w4[k4];
      FMA4(acc, w.x, &z2S[(4*k4+0)*8 + rh]);
      FMA4(acc, w.y, &z2S[(4*k4+1)*8 + rh]);
      FMA4(acc, w.z, &z2S[(4*k4+2)*8 + rh]);
      FMA4(acc, w.w, &z2S[(4*k4+3)*8 + rh]);
    }
    #pragma unroll
    for (int j = 0; j < 4; ++j) hF[0][bidx(8 + o, rh + j)] = f2h(acc[j]);
  } else if (t < 192) {                // x part -> k = 0..7, buffer 0
    int tt2 = t - 128; int r = tt2 >> 3, k = tt2 & 7;
    hF[0][bidx(k, r)] = f2h(xS[k*8 + r]);
  }

  // ---------------- weights as fp16 A-fragments (gate-permuted rows) ----------------
  // n' = 4*unit + gate ; src row = gate*72 + unit. A[row=n'][k], k = kt*32+q_a*8+j.
  half8 Af[2][3];
  f32x4 biasq[2];
  #pragma unroll
  for (int i = 0; i < 2; ++i) {
    int u = 4*(2*wv + i) + q_a;
    biasq[i].x = b_ih[u]       + b_hh[u];
    biasq[i].y = b_ih[72 + u]  + b_hh[72 + u];
    biasq[i].z = b_ih[144 + u] + b_hh[144 + u];
    biasq[i].w = b_ih[216 + u] + b_hh[216 + u];
    int nprime = (2*wv + i)*16 + col;
    int srcrow = (nprime & 3)*72 + (nprime >> 2);
    #pragma unroll
    for (int kt = 0; kt < 3; ++kt) {
      union { unsigned short u16[8]; half8 h; } cw;
      #pragma unroll
      for (int j = 0; j < 8; ++j) {
        int k = kt*32 + q_a*8 + j;
        float v = 0.f;
        if (k < 72)      v = W_hh[srcrow*HH + k];
        else if (k < 81) v = W_ih[srcrow*9 + (k - 72)];
        cw.u16[j] = f2h(v);
      }
      Af[i][kt] = cw.h;
    }
  }

  // ---------------- LSTM over time: one lgkm barrier per step ----------------
#define MFMA16(A, B, C) __builtin_amdgcn_mfma_f32_16x16x32_f16(A, B, C, 0, 0, 0)
  const f32x4 zero4 = {0.f, 0.f, 0.f, 0.f};
#define STEP(PAR) { \
    const unsigned short* hb = &hF[PAR][0]; \
    unsigned short* hn = &hF[(PAR) ^ 1][0]; \
    half8 bf0 = *(const half8*)(hb + bOff0); \
    half8 bf1 = *(const half8*)(hb + bOff1); \
    half8 bf2 = *(const half8*)(hb + bOff2); \
    f32x4 x0 = MFMA16(Af[0][0], bf0, biasq[0]); \
    f32x4 x1 = MFMA16(Af[1][0], bf0, biasq[1]); \
    f32x4 y0 = MFMA16(Af[0][1], bf1, zero4); \
    f32x4 y1 = MFMA16(Af[1][1], bf1, zero4); \
    x0 = MFMA16(Af[0][2], bf2, x0); \
    x1 = MFMA16(Af[1][2], bf2, x1); \
    f32x4 a0 = x0 + y0; \
    f32x4 a1 = x1 + y1; \
    float ig = gHi ? a1.x : a0.x, fg = gHi ? a1.y : a0.y; \
    float gg = gHi ? a1.z : a0.z, og = gHi ? a1.w : a0.w; \
    float hv = cellUpd(ig, fg, gg, og, cstA); \
    hn[ibA] = f2h(hv); \
    hvP = (step == cidxm1) ? hv : hvP; \
    hvC = (step == cidxE)  ? hv : hvC; \
    if (doXt && tc < 31) hn[xtDst] = f2h(rnnS[xtSrc + (tc + 1)*9]); \
    BARL(); \
    ++tc; ++step; }

  int step = 0;
  for (int chunk = 0; chunk*32 <= maxIdx; ++chunk) {
    BARL();                                    // prior chunk / encoder reads of rnnS done
    *(float4*)&rnnS[pfR*292 + pfP*4] = pf;     // commit prefetched chunk (vmcnt wait here)
    if ((chunk + 1)*32 <= maxIdx) pf = rnnRow[(chunk + 1)*72];  // issue next early
    BARL();
    if (doXt) hF[0][xtDst] = f2h(rnnS[xtSrc]); // xt for first step of chunk (par==0)
    BARL();
    const int lim = min(31, maxIdx - chunk*32);
    int tc = 0;
    while (tc + 1 <= lim) { STEP(0) STEP(1) }
    if (tc <= lim) { STEP(0) }                 // odd tail only possible on the last chunk
  }
#undef STEP
#undef MFMA16

  // flush snapshots (each lane owns one distinct (unit,row) cell)
  snapP[cL][uA] = hvP;  snapC[cL][uA] = hvC;
  if (t < NR) dS[t] = deltas[brS[t]*TT + idxS[t]];
  __syncthreads();

  // ---------------- decoder: 72 -> 288 -> 288 -> 8 ----------------
  { // build dec_in into hS[u][r]  (576 elements, one per thread)
    int u = t % 72, r = t / 72;
    float d = dS[r];
    float sp = snapP[r][u], sc = snapC[r][u];
    hS[u*8 + r] = fmaf(d, sc - sp, sp);
  }
  __syncthreads();

  // layer1: 288 x 72  (all 576 threads: n = t>>1, half-row rh)
  float* d1S = rnnS; // [n][8]
  {
    int n = t >> 1, rh = (t & 1)*4;
    float acc[4];
    float b = db1[n];
    acc[0]=b; acc[1]=b; acc[2]=b; acc[3]=b;
    const float4* w4 = (const float4*)(dW1 + n*HH);
    #pragma unroll 2
    for (int k4 = 0; k4 < 18; ++k4) {
      float4 w = w4[k4];
      FMA4(acc, w.x, &hS[(4*k4+0)*8 + rh]);
      FMA4(acc, w.y, &hS[(4*k4+1)*8 + rh]);
      FMA4(acc, w.z, &hS[(4*k4+2)*8 + rh]);
      FMA4(acc, w.w, &hS[(4*k4+3)*8 + rh]);
    }
    #pragma unroll
    for (int j = 0; j < 4; ++j) d1S[n*8 + rh + j] = ftanh(acc[j]);
  }
  __syncthreads();

  // layer2: 288 x 288
  float* d2S = gS;   // [n][8]
  {
    int n = t >> 1, rh = (t & 1)*4;
    float acc[4];
    float b = db2[n];
    acc[0]=b; acc[1]=b; acc[2]=b; acc[3]=b;
    const float4* w4 = (const float4*)(dW2 + n*288);
    #pragma unroll 4
    for (int k4 = 0; k4 < 72; ++k4) {
      float4 w = w4[k4];
      FMA4(acc, w.x, &d1S[(4*k4+0)*8 + rh]);
      FMA4(acc, w.y, &d1S[(4*k4+1)*8 + rh]);
      FMA4(acc, w.z, &d1S[(4*k4+2)*8 + rh]);
      FMA4(acc, w.w, &d1S[(4*k4+3)*8 + rh]);
    }
    #pragma unroll
    for (int j = 0; j < 4; ++j) d2S[n*8 + rh + j] = ftanh(acc[j]);
  }
  __syncthreads();

  // layer3: 8 x 288 (linear) + scatter store
  if (t < 64) {
    int o = t & 7, r = t >> 3;
    float acc3 = db3[o];
    const float* wr = dW3 + o*288;
    #pragma unroll 4
    for (int k = 0; k < 288; ++k) acc3 = fmaf(wr[k], d2S[k*8 + r], acc3);
    out[brS[r]*8 + o] = acc3;
  }
}

extern "C" void kernel_launch(void* const* d_in, const int* in_sizes, int n_in,
                              void* d_out, int out_size, void* d_ws, size_t ws_size,
                              hipStream_t stream) {
  const float* x      = (const float*)d_in[0];
  const float* rnn    = (const float*)d_in[1];
  const float* deltas = (const float*)d_in[2];
  const int*   h_lens = (const int*)  d_in[3];
  const float* W_ih   = (const float*)d_in[4];
  const float* W_hh   = (const float*)d_in[5];
  const float* b_ih   = (const float*)d_in[6];
  const float* b_hh   = (const float*)d_in[7];
  const float* eW1    = (const float*)d_in[8];
  const float* eb1    = (const float*)d_in[9];
  const float* eW2    = (const float*)d_in[10];
  const float* eb2    = (const float*)d_in[11];
  const float* eW3    = (const float*)d_in[12];
  const float* eb3    = (const float*)d_in[13];
  const float* dW1    = (const float*)d_in[14];
  const float* db1    = (const float*)d_in[15];
  const float* dW2    = (const float*)d_in[16];
  const float* db2    = (const float*)d_in[17];
  const float* dW3    = (const float*)d_in[18];
  const float* db3    = (const float*)d_in[19];
  float* out = (float*)d_out;

  int* perm = nullptr;
  if (ws_size >= 2048 * sizeof(int)) {
    perm = (int*)d_ws;
    cfm_sort<<<1, 256, 0, stream>>>(h_lens, perm);
  }
  cfm_main<<<NBLK, NTH, 0, stream>>>(x, rnn, deltas, h_lens, W_ih, W_hh, b_ih, b_hh,
                                     eW1, eb1, eW2, eb2, eW3, eb3,
                                     dW1, db1, dW2, db2, dW3, db3,
                                     perm, out);
}

// Round 8
// 375.561 us; speedup vs baseline: 1.5289x; 1.0412x over previous
//
#include <hip/hip_runtime.h>
#include <cstdint>

#define HH 72
#define NR 8
#define NTH 576
#define NBLK 256
#define TT 512

typedef __attribute__((ext_vector_type(8))) _Float16 half8;
typedef __attribute__((ext_vector_type(4))) float f32x4;

#if __has_builtin(__builtin_amdgcn_exp2f)
#define EXP2(x) __builtin_amdgcn_exp2f(x)
#else
#define EXP2(x) exp2f(x)
#endif
#if __has_builtin(__builtin_amdgcn_rcpf)
#define RCP(x) __builtin_amdgcn_rcpf(x)
#else
#define RCP(x) (1.0f/(x))
#endif

__device__ __forceinline__ float fsig(float x) {
  float e = EXP2(x * -1.442695040888963f);
  return RCP(1.0f + e);
}
__device__ __forceinline__ float ftanh(float x) {
  float e = EXP2(x * -2.885390081777927f);
  return fmaf(2.0f, RCP(1.0f + e), -1.0f);
}

// fp32 -> fp16 bits (RNE via v_cvt_f16_f32)
__device__ __forceinline__ unsigned short f2h(float v) {
  union { _Float16 h; unsigned short u; } cv;
  cv.h = (_Float16)v;
  return cv.u;
}

// fragment ushort index for contraction-dim k, batch col m (0..7).
// Layout [kt*4+q][m=8][8]: 8 contiguous fp16 -> one ds_read_b128 per (group,m).
__device__ __forceinline__ int bidx(int k, int m) {
  return ((k >> 5)*4 + ((k >> 3) & 3))*64 + m*8 + (k & 7);
}

__device__ __forceinline__ float cellUpd(float ig, float fg, float gg, float og, float& c) {
  c = fmaf(fsig(fg), c, fsig(ig)*ftanh(gg));
  return fsig(og)*ftanh(c);
}

// accumulate 4 rows: A[r] += W_ * P_[r]
#define FMA4(A, W_, P_) { \
  const float4 _fa = *(const float4*)(P_); \
  A[0] = fmaf((W_), _fa.x, A[0]); A[1] = fmaf((W_), _fa.y, A[1]); \
  A[2] = fmaf((W_), _fa.z, A[2]); A[3] = fmaf((W_), _fa.w, A[3]); }

// counting sort of rows by h_lens (ascending) -> blocks get similar-length rows
__global__ void cfm_sort(const int* __restrict__ h_lens, int* __restrict__ perm) {
  __shared__ int hist[257];
  __shared__ int offs[257];
  const int t = threadIdx.x; // 256
  for (int i = t; i < 257; i += 256) hist[i] = 0;
  __syncthreads();
  for (int i = t; i < 2048; i += 256) {
    int bkt = min(max(h_lens[i] - 256, 0), 256);
    atomicAdd(&hist[bkt], 1);
  }
  __syncthreads();
  if (t == 0) { int s = 0; for (int i = 0; i < 257; ++i) { offs[i] = s; s += hist[i]; } }
  __syncthreads();
  for (int i = t; i < 2048; i += 256) {
    int bkt = min(max(h_lens[i] - 256, 0), 256);
    int pos = atomicAdd(&offs[bkt], 1);
    perm[pos] = i;
  }
}

// NR=8 rows/block, 256 blocks (1/CU), 9 waves x 2 tiles (the 269us R1 structure).
// Single delta vs R1: the xt-staging LDS read is hoisted to the TOP of the step
// (issued with the bf reads, latency hidden under MFMA+activation) instead of
// sitting as a dependent read->cvt->write chain right before the barrier on the
// straggler waves 0-1.
__global__ __launch_bounds__(NTH, 2)
void cfm_main(const float* __restrict__ x, const float* __restrict__ rnn,
              const float* __restrict__ deltas, const int* __restrict__ h_lens,
              const float* __restrict__ W_ih, const float* __restrict__ W_hh,
              const float* __restrict__ b_ih, const float* __restrict__ b_hh,
              const float* __restrict__ eW1, const float* __restrict__ eb1,
              const float* __restrict__ eW2, const float* __restrict__ eb2,
              const float* __restrict__ eW3, const float* __restrict__ eb3,
              const float* __restrict__ dW1, const float* __restrict__ db1,
              const float* __restrict__ dW2, const float* __restrict__ db2,
              const float* __restrict__ dW3, const float* __restrict__ db3,
              const int* __restrict__ perm, float* __restrict__ out)
{
  __shared__ __align__(16) unsigned short hF[2][768];  // fp16 [h|xt|pad] B-fragments, dbuf
  __shared__ __align__(16) float gS[2304];             // enc z1S / dec d2S  [n][8]
  __shared__ __align__(16) float rnnS[2336];           // rnn chunk [8][292]; enc z2S / dec d1S
  __shared__ __align__(16) float snapP[NR][HH];
  __shared__ __align__(16) float snapC[NR][HH];
  __shared__ __align__(16) float hS[HH*NR];            // decoder dec_in [u][r]
  __shared__ __align__(16) float xS[8*NR];             // [k][r]
  __shared__ int brS[NR];
  __shared__ int idxS[NR];
  __shared__ float dS[NR];

  const int t  = threadIdx.x;
  const int bb = blockIdx.x;

  for (int i = t; i < 768; i += NTH) ((unsigned*)hF)[i] = 0;  // zero both buffers (pads!)

  if (t < NR) {
    int row = perm ? perm[bb*NR + t] : (bb*NR + t);
    brS[t]  = row;
    idxS[t] = h_lens[row] - 1;   // in [255, 511]
  }
  __syncthreads();

  int maxIdx = idxS[0];
  #pragma unroll
  for (int r = 1; r < NR; ++r) maxIdx = max(maxIdx, idxS[r]);

  const int lane = t & 63;
  const int wv   = t >> 6;                 // 0..8, tiles {2wv, 2wv+1}
  const int col  = lane & 15;
  const int q_a  = lane >> 4;
  const int cL   = col & 7;                // batch col
  const int gHi  = col >> 3;               // which of my wave's 2 tiles
  const int uA   = 4*(2*wv + gHi) + q_a;   // unit owned
  const int cidxE  = idxS[cL];
  const int cidxm1 = cidxE - 1;
  const int ibA  = bidx(uA, cL);
  const int bOff0 = (0*4 + q_a)*64 + cL*8; // broadcast read: col&7
  const int bOff1 = (1*4 + q_a)*64 + cL*8;
  const int bOff2 = (2*4 + q_a)*64 + cL*8;
  float cstA = 0.f;

  // prefetch rnn chunk 0 into regs (1 float4 per thread: 576*16B = 8 rows * 288 floats)
  const int pfR = t / 72;
  const int pfP = t - pfR*72;
  const float4* rnnRow = (const float4*)(rnn + (size_t)brS[pfR]*4608) + pfP;
  float4 pf = rnnRow[0];

  // xt staging lanes: 72 values/step (8 rows x 9 k)
  const bool doXt = (t < 72);
  int xtDst = 0, xtSrc = 0;
  if (doXt) {
    int rX = t / 9, kX = t - rX*9;
    xtDst = bidx(72 + kX, rX);
    xtSrc = rX*292 + kX;          // padded row stride 292 -> spreads banks
  }

  // ---------------- encoder: 8 -> 256 -> 256 -> 64 ----------------
  if (t < 64) { int r = t >> 3, k = t & 7; xS[k*8 + r] = x[brS[r]*8 + k]; }
  __syncthreads();

  float* z1S = gS;   // [n][8]
  if (t < 512) {
    int n = t >> 1, rh = (t & 1)*4;
    float acc[4];
    float b = eb1[n];
    acc[0]=b; acc[1]=b; acc[2]=b; acc[3]=b;
    #pragma unroll
    for (int k = 0; k < 8; ++k) { float w = eW1[n*8 + k]; FMA4(acc, w, &xS[k*8 + rh]); }
    #pragma unroll
    for (int j = 0; j < 4; ++j) z1S[n*8 + rh + j] = ftanh(acc[j]);
  }
  __syncthreads();
  float* z2S = rnnS; // [n][8]
  if (t < 512) {
    int n = t >> 1, rh = (t & 1)*4;
    float acc[4];
    float b = eb2[n];
    acc[0]=b; acc[1]=b; acc[2]=b; acc[3]=b;
    const float4* w4 = (const float4*)(eW2 + n*256);
    #pragma unroll 4
    for (int k4 = 0; k4 < 64; ++k4) {
      float4 w = w4[k4];
      FMA4(acc, w.x, &z1S[(4*k4+0)*8 + rh]);
      FMA4(acc, w.y, &z1S[(4*k4+1)*8 + rh]);
      FMA4(acc, w.z, &z1S[(4*k4+2)*8 + rh]);
      FMA4(acc, w.w, &z1S[(4*k4+3)*8 + rh]);
    }
    #pragma unroll
    for (int j = 0; j < 4; ++j) z2S[n*8 + rh + j] = ftanh(acc[j]);
  }
  __syncthreads();
  if (t < 128) {                       // h0 (linear) -> fragment k = 8+o, buffer 0
    int o = t >> 1, rh = (t & 1)*4;
    float acc[4];
    float b = eb3[o];
    acc[0]=b; acc[1]=b; acc[2]=b; acc[3]=b;
    const float4* w4 = (const float4*)(eW3 + o*256);
    #pragma unroll 4
    for (int k4 = 0; k4 < 64; ++k4) {
      float4 w = w4[k4];
      FMA4(acc, w.x, &z2S[(4*k4+0)*8 + rh]);
      FMA4(acc, w.y, &z2S[(4*k4+1)*8 + rh]);
      FMA4(acc, w.z, &z2S[(4*k4+2)*8 + rh]);
      FMA4(acc, w.w, &z2S[(4*k4+3)*8 + rh]);
    }
    #pragma unroll
    for (int j = 0; j < 4; ++j) hF[0][bidx(8 + o, rh + j)] = f2h(acc[j]);
  } else if (t < 192) {                // x part -> k = 0..7, buffer 0
    int tt2 = t - 128; int r = tt2 >> 3, k = tt2 & 7;
    hF[0][bidx(k, r)] = f2h(xS[k*8 + r]);
  }

  // ---------------- weights as fp16 A-fragments (gate-permuted rows) ----------------
  // n' = 4*unit + gate ; src row = gate*72 + unit. A[row=n'][k], k = kt*32+q_a*8+j.
  half8 Af[2][3];
  f32x4 biasq[2];
  #pragma unroll
  for (int i = 0; i < 2; ++i) {
    int u = 4*(2*wv + i) + q_a;
    biasq[i].x = b_ih[u]       + b_hh[u];
    biasq[i].y = b_ih[72 + u]  + b_hh[72 + u];
    biasq[i].z = b_ih[144 + u] + b_hh[144 + u];
    biasq[i].w = b_ih[216 + u] + b_hh[216 + u];
    int nprime = (2*wv + i)*16 + col;
    int srcrow = (nprime & 3)*72 + (nprime >> 2);
    #pragma unroll
    for (int kt = 0; kt < 3; ++kt) {
      union { unsigned short u16[8]; half8 h; } cw;
      #pragma unroll
      for (int j = 0; j < 8; ++j) {
        int k = kt*32 + q_a*8 + j;
        float v = 0.f;
        if (k < 72)      v = W_hh[srcrow*HH + k];
        else if (k < 81) v = W_ih[srcrow*9 + (k - 72)];
        cw.u16[j] = f2h(v);
      }
      Af[i][kt] = cw.h;
    }
  }

  // ---------------- LSTM over time: one barrier per step ----------------
  // Step PAR: read hF[PAR], write hF[PAR^1]. Chunks are 32 steps, par returns to 0.
#define MFMA16(A, B, C) __builtin_amdgcn_mfma_f32_16x16x32_f16(A, B, C, 0, 0, 0)
#define STEP(PAR) { \
    const unsigned short* hb = &hF[PAR][0]; \
    unsigned short* hn = &hF[(PAR) ^ 1][0]; \
    float xtv = 0.f; \
    if (doXt) { int xtN = (tc < 31) ? (tc + 1) : 31; xtv = rnnS[xtSrc + xtN*9]; } \
    half8 bf0 = *(const half8*)(hb + bOff0); \
    half8 bf1 = *(const half8*)(hb + bOff1); \
    half8 bf2 = *(const half8*)(hb + bOff2); \
    f32x4 a0 = MFMA16(Af[0][0], bf0, biasq[0]); \
    f32x4 a1 = MFMA16(Af[1][0], bf0, biasq[1]); \
    a0 = MFMA16(Af[0][1], bf1, a0);  a1 = MFMA16(Af[1][1], bf1, a1); \
    a0 = MFMA16(Af[0][2], bf2, a0);  a1 = MFMA16(Af[1][2], bf2, a1); \
    float ig = gHi ? a1.x : a0.x; \
    float fg = gHi ? a1.y : a0.y; \
    float gg = gHi ? a1.z : a0.z; \
    float og = gHi ? a1.w : a0.w; \
    float hv = cellUpd(ig, fg, gg, og, cstA); \
    hn[ibA] = f2h(hv); \
    if (step == cidxm1) snapP[cL][uA] = hv; \
    if (step == cidxE)  snapC[cL][uA] = hv; \
    if (doXt && tc < 31) hn[xtDst] = f2h(xtv); \
    __syncthreads(); \
    ++tc; ++step; }

  int step = 0;
  int par = 0;
  for (int chunk = 0; chunk*32 <= maxIdx; ++chunk) {
    __syncthreads();                         // prior chunk / encoder reads of rnnS done
    *(float4*)&rnnS[pfR*292 + pfP*4] = pf;   // commit prefetched chunk
    if ((chunk + 1)*32 <= maxIdx) pf = rnnRow[(chunk + 1)*72];  // issue next early
    __syncthreads();
    if (doXt) hF[0][xtDst] = f2h(rnnS[xtSrc]);   // xt for first step of chunk (par==0)
    __syncthreads();
    const int lim = min(31, maxIdx - chunk*32);
    int tc = 0;
    while (tc + 1 <= lim) { STEP(0) STEP(1) }
    if (tc <= lim) { STEP(0) }               // odd tail only possible on the last chunk
  }
#undef STEP
#undef MFMA16
  (void)par;

  // ---------------- decoder: 72 -> 288 -> 288 -> 8 ----------------
  if (t < NR) dS[t] = deltas[brS[t]*TT + idxS[t]];
  __syncthreads();

  { // build dec_in into hS[u][r]  (576 elements, one per thread)
    int u = t % 72, r = t / 72;
    float d = dS[r];
    float sp = snapP[r][u], sc = snapC[r][u];
    hS[u*8 + r] = fmaf(d, sc - sp, sp);
  }
  __syncthreads();

  // layer1: 288 x 72  (all 576 threads: n = t>>1, half-row rh)
  float* d1S = rnnS; // [n][8]
  {
    int n = t >> 1, rh = (t & 1)*4;
    float acc[4];
    float b = db1[n];
    acc[0]=b; acc[1]=b; acc[2]=b; acc[3]=b;
    const float4* w4 = (const float4*)(dW1 + n*HH);
    #pragma unroll 2
    for (int k4 = 0; k4 < 18; ++k4) {
      float4 w = w4[k4];
      FMA4(acc, w.x, &hS[(4*k4+0)*8 + rh]);
      FMA4(acc, w.y, &hS[(4*k4+1)*8 + rh]);
      FMA4(acc, w.z, &hS[(4*k4+2)*8 + rh]);
      FMA4(acc, w.w, &hS[(4*k4+3)*8 + rh]);
    }
    #pragma unroll
    for (int j = 0; j < 4; ++j) d1S[n*8 + rh + j] = ftanh(acc[j]);
  }
  __syncthreads();

  // layer2: 288 x 288
  float* d2S = gS;   // [n][8]
  {
    int n = t >> 1, rh = (t & 1)*4;
    float acc[4];
    float b = db2[n];
    acc[0]=b; acc[1]=b; acc[2]=b; acc[3]=b;
    const float4* w4 = (const float4*)(dW2 + n*288);
    #pragma unroll 4
    for (int k4 = 0; k4 < 72; ++k4) {
      float4 w = w4[k4];
      FMA4(acc, w.x, &d1S[(4*k4+0)*8 + rh]);
      FMA4(acc, w.y, &d1S[(4*k4+1)*8 + rh]);
      FMA4(acc, w.z, &d1S[(4*k4+2)*8 + rh]);
      FMA4(acc, w.w, &d1S[(4*k4+3)*8 + rh]);
    }
    #pragma unroll
    for (int j = 0; j < 4; ++j) d2S[n*8 + rh + j] = ftanh(acc[j]);
  }
  __syncthreads();

  // layer3: 8 x 288 (linear) + scatter store
  if (t < 64) {
    int o = t & 7, r = t >> 3;
    float acc3 = db3[o];
    const float* wr = dW3 + o*288;
    #pragma unroll 4
    for (int k = 0; k < 288; ++k) acc3 = fmaf(wr[k], d2S[k*8 + r], acc3);
    out[brS[r]*8 + o] = acc3;
  }
}

extern "C" void kernel_launch(void* const* d_in, const int* in_sizes, int n_in,
                              void* d_out, int out_size, void* d_ws, size_t ws_size,
                              hipStream_t stream) {
  const float* x      = (const float*)d_in[0];
  const float* rnn    = (const float*)d_in[1];
  const float* deltas = (const float*)d_in[2];
  const int*   h_lens = (const int*)  d_in[3];
  const float* W_ih   = (const float*)d_in[4];
  const float* W_hh   = (const float*)d_in[5];
  const float* b_ih   = (const float*)d_in[6];
  const float* b_hh   = (const float*)d_in[7];
  const float* eW1    = (const float*)d_in[8];
  const float* eb1    = (const float*)d_in[9];
  const float* eW2    = (const float*)d_in[10];
  const float* eb2    = (const float*)d_in[11];
  const float* eW3    = (const float*)d_in[12];
  const float* eb3    = (const float*)d_in[13];
  const float* dW1    = (const float*)d_in[14];
  const float* db1    = (const float*)d_in[15];
  const float* dW2    = (const float*)d_in[16];
  const float* db2    = (const float*)d_in[17];
  const float* dW3    = (const float*)d_in[18];
  const float* db3    = (const float*)d_in[19];
  float* out = (float*)d_out;

  int* perm = nullptr;
  if (ws_size >= 2048 * sizeof(int)) {
    perm = (int*)d_ws;
    cfm_sort<<<1, 256, 0, stream>>>(h_lens, perm);
  }
  cfm_main<<<NBLK, NTH, 0, stream>>>(x, rnn, deltas, h_lens, W_ih, W_hh, b_ih, b_hh,
                                     eW1, eb1, eW2, eb2, eW3, eb3,
                                     dW1, db1, dW2, db2, dW3, db3,
                                     perm, out);
}

// Round 9
// 357.116 us; speedup vs baseline: 1.6079x; 1.0517x over previous
//
#include <hip/hip_runtime.h>
#include <cstdint>

#define HH 72
#define NR 8
#define NTH 576
#define NBLK 256
#define TT 512

typedef __attribute__((ext_vector_type(8))) _Float16 half8;
typedef __attribute__((ext_vector_type(4))) float f32x4;

#if __has_builtin(__builtin_amdgcn_exp2f)
#define EXP2(x) __builtin_amdgcn_exp2f(x)
#else
#define EXP2(x) exp2f(x)
#endif
#if __has_builtin(__builtin_amdgcn_rcpf)
#define RCP(x) __builtin_amdgcn_rcpf(x)
#else
#define RCP(x) (1.0f/(x))
#endif

__device__ __forceinline__ float fsig(float x) {
  float e = EXP2(x * -1.442695040888963f);
  return RCP(1.0f + e);
}
__device__ __forceinline__ float ftanh(float x) {
  float e = EXP2(x * -2.885390081777927f);
  return fmaf(2.0f, RCP(1.0f + e), -1.0f);
}

// fp32 -> fp16 bits (RNE via v_cvt_f16_f32)
__device__ __forceinline__ unsigned short f2h(float v) {
  union { _Float16 h; unsigned short u; } cv;
  cv.h = (_Float16)v;
  return cv.u;
}

// fragment ushort index for contraction-dim k, batch col m (0..7).
// Layout [kt*4+q][m=8][8]: 8 contiguous fp16 -> one ds_read_b128 per (group,m).
__device__ __forceinline__ int bidx(int k, int m) {
  return ((k >> 5)*4 + ((k >> 3) & 3))*64 + m*8 + (k & 7);
}

__device__ __forceinline__ float cellUpd(float ig, float fg, float gg, float og, float& c) {
  c = fmaf(fsig(fg), c, fsig(ig)*ftanh(gg));
  return fsig(og)*ftanh(c);
}

// accumulate 4 rows: A[r] += W_ * P_[r]
#define FMA4(A, W_, P_) { \
  const float4 _fa = *(const float4*)(P_); \
  A[0] = fmaf((W_), _fa.x, A[0]); A[1] = fmaf((W_), _fa.y, A[1]); \
  A[2] = fmaf((W_), _fa.z, A[2]); A[3] = fmaf((W_), _fa.w, A[3]); }

// counting sort of rows by h_lens (ascending) -> blocks get similar-length rows
__global__ void cfm_sort(const int* __restrict__ h_lens, int* __restrict__ perm) {
  __shared__ int hist[257];
  __shared__ int offs[257];
  const int t = threadIdx.x; // 256
  for (int i = t; i < 257; i += 256) hist[i] = 0;
  __syncthreads();
  for (int i = t; i < 2048; i += 256) {
    int bkt = min(max(h_lens[i] - 256, 0), 256);
    atomicAdd(&hist[bkt], 1);
  }
  __syncthreads();
  if (t == 0) { int s = 0; for (int i = 0; i < 257; ++i) { offs[i] = s; s += hist[i]; } }
  __syncthreads();
  for (int i = t; i < 2048; i += 256) {
    int bkt = min(max(h_lens[i] - 256, 0), 256);
    int pos = atomicAdd(&offs[bkt], 1);
    perm[pos] = i;
  }
}

// NR=8 rows/block, 256 blocks (1/CU), 9 waves x 2 tiles (the 269us R1 structure).
// SINGLE delta vs R1: xt-staging lanes moved from t<72 (wave 0 on the 3-wave
// straggler SIMD0 {w0,w4,w8}) to t in [64,136) (wave 1 / SIMD1 + 8 lanes of
// wave 2 / SIMD2) -> SIMD0's three waves run the bare step program.
__global__ __launch_bounds__(NTH, 2)
void cfm_main(const float* __restrict__ x, const float* __restrict__ rnn,
              const float* __restrict__ deltas, const int* __restrict__ h_lens,
              const float* __restrict__ W_ih, const float* __restrict__ W_hh,
              const float* __restrict__ b_ih, const float* __restrict__ b_hh,
              const float* __restrict__ eW1, const float* __restrict__ eb1,
              const float* __restrict__ eW2, const float* __restrict__ eb2,
              const float* __restrict__ eW3, const float* __restrict__ eb3,
              const float* __restrict__ dW1, const float* __restrict__ db1,
              const float* __restrict__ dW2, const float* __restrict__ db2,
              const float* __restrict__ dW3, const float* __restrict__ db3,
              const int* __restrict__ perm, float* __restrict__ out)
{
  __shared__ __align__(16) unsigned short hF[2][768];  // fp16 [h|xt|pad] B-fragments, dbuf
  __shared__ __align__(16) float gS[2304];             // enc z1S / dec d2S  [n][8]
  __shared__ __align__(16) float rnnS[2336];           // rnn chunk [8][292]; enc z2S / dec d1S
  __shared__ __align__(16) float snapP[NR][HH];
  __shared__ __align__(16) float snapC[NR][HH];
  __shared__ __align__(16) float hS[HH*NR];            // decoder dec_in [u][r]
  __shared__ __align__(16) float xS[8*NR];             // [k][r]
  __shared__ int brS[NR];
  __shared__ int idxS[NR];
  __shared__ float dS[NR];

  const int t  = threadIdx.x;
  const int bb = blockIdx.x;

  for (int i = t; i < 768; i += NTH) ((unsigned*)hF)[i] = 0;  // zero both buffers (pads!)

  if (t < NR) {
    int row = perm ? perm[bb*NR + t] : (bb*NR + t);
    brS[t]  = row;
    idxS[t] = h_lens[row] - 1;   // in [255, 511]
  }
  __syncthreads();

  int maxIdx = idxS[0];
  #pragma unroll
  for (int r = 1; r < NR; ++r) maxIdx = max(maxIdx, idxS[r]);

  const int lane = t & 63;
  const int wv   = t >> 6;                 // 0..8, tiles {2wv, 2wv+1}
  const int col  = lane & 15;
  const int q_a  = lane >> 4;
  const int cL   = col & 7;                // batch col
  const int gHi  = col >> 3;               // which of my wave's 2 tiles
  const int uA   = 4*(2*wv + gHi) + q_a;   // unit owned
  const int cidxE  = idxS[cL];
  const int cidxm1 = cidxE - 1;
  const int ibA  = bidx(uA, cL);
  const int bOff0 = (0*4 + q_a)*64 + cL*8; // broadcast read: col&7
  const int bOff1 = (1*4 + q_a)*64 + cL*8;
  const int bOff2 = (2*4 + q_a)*64 + cL*8;
  float cstA = 0.f;

  // prefetch rnn chunk 0 into regs (1 float4 per thread: 576*16B = 8 rows * 288 floats)
  const int pfR = t / 72;
  const int pfP = t - pfR*72;
  const float4* rnnRow = (const float4*)(rnn + (size_t)brS[pfR]*4608) + pfP;
  float4 pf = rnnRow[0];

  // xt staging lanes: 72 values/step (8 rows x 9 k) on waves 1..2 (SIMD1/SIMD2),
  // keeping the 3-wave straggler SIMD0 {w0,w4,w8} free of side jobs.
  const bool doXt = (t >= 64) && (t < 136);
  int xtDst = 0, xtSrc = 0;
  if (doXt) {
    int e = t - 64;
    int rX = e / 9, kX = e - rX*9;
    xtDst = bidx(72 + kX, rX);
    xtSrc = rX*292 + kX;          // padded row stride 292 -> spreads banks
  }

  // ---------------- encoder: 8 -> 256 -> 256 -> 64 ----------------
  if (t < 64) { int r = t >> 3, k = t & 7; xS[k*8 + r] = x[brS[r]*8 + k]; }
  __syncthreads();

  float* z1S = gS;   // [n][8]
  if (t < 512) {
    int n = t >> 1, rh = (t & 1)*4;
    float acc[4];
    float b = eb1[n];
    acc[0]=b; acc[1]=b; acc[2]=b; acc[3]=b;
    #pragma unroll
    for (int k = 0; k < 8; ++k) { float w = eW1[n*8 + k]; FMA4(acc, w, &xS[k*8 + rh]); }
    #pragma unroll
    for (int j = 0; j < 4; ++j) z1S[n*8 + rh + j] = ftanh(acc[j]);
  }
  __syncthreads();
  float* z2S = rnnS; // [n][8]
  if (t < 512) {
    int n = t >> 1, rh = (t & 1)*4;
    float acc[4];
    float b = eb2[n];
    acc[0]=b; acc[1]=b; acc[2]=b; acc[3]=b;
    const float4* w4 = (const float4*)(eW2 + n*256);
    #pragma unroll 4
    for (int k4 = 0; k4 < 64; ++k4) {
      float4 w = w4[k4];
      FMA4(acc, w.x, &z1S[(4*k4+0)*8 + rh]);
      FMA4(acc, w.y, &z1S[(4*k4+1)*8 + rh]);
      FMA4(acc, w.z, &z1S[(4*k4+2)*8 + rh]);
      FMA4(acc, w.w, &z1S[(4*k4+3)*8 + rh]);
    }
    #pragma unroll
    for (int j = 0; j < 4; ++j) z2S[n*8 + rh + j] = ftanh(acc[j]);
  }
  __syncthreads();
  if (t < 128) {                       // h0 (linear) -> fragment k = 8+o, buffer 0
    int o = t >> 1, rh = (t & 1)*4;
    float acc[4];
    float b = eb3[o];
    acc[0]=b; acc[1]=b; acc[2]=b; acc[3]=b;
    const float4* w4 = (const float4*)(eW3 + o*256);
    #pragma unroll 4
    for (int k4 = 0; k4 < 64; ++k4) {
      float4 w = w4[k4];
      FMA4(acc, w.x, &z2S[(4*k4+0)*8 + rh]);
      FMA4(acc, w.y, &z2S[(4*k4+1)*8 + rh]);
      FMA4(acc, w.z, &z2S[(4*k4+2)*8 + rh]);
      FMA4(acc, w.w, &z2S[(4*k4+3)*8 + rh]);
    }
    #pragma unroll
    for (int j = 0; j < 4; ++j) hF[0][bidx(8 + o, rh + j)] = f2h(acc[j]);
  } else if (t < 192) {                // x part -> k = 0..7, buffer 0
    int tt2 = t - 128; int r = tt2 >> 3, k = tt2 & 7;
    hF[0][bidx(k, r)] = f2h(xS[k*8 + r]);
  }

  // ---------------- weights as fp16 A-fragments (gate-permuted rows) ----------------
  // n' = 4*unit + gate ; src row = gate*72 + unit. A[row=n'][k], k = kt*32+q_a*8+j.
  half8 Af[2][3];
  f32x4 biasq[2];
  #pragma unroll
  for (int i = 0; i < 2; ++i) {
    int u = 4*(2*wv + i) + q_a;
    biasq[i].x = b_ih[u]       + b_hh[u];
    biasq[i].y = b_ih[72 + u]  + b_hh[72 + u];
    biasq[i].z = b_ih[144 + u] + b_hh[144 + u];
    biasq[i].w = b_ih[216 + u] + b_hh[216 + u];
    int nprime = (2*wv + i)*16 + col;
    int srcrow = (nprime & 3)*72 + (nprime >> 2);
    #pragma unroll
    for (int kt = 0; kt < 3; ++kt) {
      union { unsigned short u16[8]; half8 h; } cw;
      #pragma unroll
      for (int j = 0; j < 8; ++j) {
        int k = kt*32 + q_a*8 + j;
        float v = 0.f;
        if (k < 72)      v = W_hh[srcrow*HH + k];
        else if (k < 81) v = W_ih[srcrow*9 + (k - 72)];
        cw.u16[j] = f2h(v);
      }
      Af[i][kt] = cw.h;
    }
  }

  // ---------------- LSTM over time: one barrier per step ----------------
  // Step PAR: read hF[PAR], write hF[PAR^1]. Chunks are 32 steps, par returns to 0.
#define MFMA16(A, B, C) __builtin_amdgcn_mfma_f32_16x16x32_f16(A, B, C, 0, 0, 0)
#define STEP(PAR) { \
    const unsigned short* hb = &hF[PAR][0]; \
    unsigned short* hn = &hF[(PAR) ^ 1][0]; \
    half8 bf0 = *(const half8*)(hb + bOff0); \
    half8 bf1 = *(const half8*)(hb + bOff1); \
    half8 bf2 = *(const half8*)(hb + bOff2); \
    f32x4 a0 = MFMA16(Af[0][0], bf0, biasq[0]); \
    f32x4 a1 = MFMA16(Af[1][0], bf0, biasq[1]); \
    a0 = MFMA16(Af[0][1], bf1, a0);  a1 = MFMA16(Af[1][1], bf1, a1); \
    a0 = MFMA16(Af[0][2], bf2, a0);  a1 = MFMA16(Af[1][2], bf2, a1); \
    float ig = gHi ? a1.x : a0.x; \
    float fg = gHi ? a1.y : a0.y; \
    float gg = gHi ? a1.z : a0.z; \
    float og = gHi ? a1.w : a0.w; \
    float hv = cellUpd(ig, fg, gg, og, cstA); \
    hn[ibA] = f2h(hv); \
    if (step == cidxm1) snapP[cL][uA] = hv; \
    if (step == cidxE)  snapC[cL][uA] = hv; \
    if (doXt && tc < 31) hn[xtDst] = f2h(rnnS[xtSrc + (tc + 1)*9]); \
    __syncthreads(); \
    ++tc; ++step; }

  int step = 0;
  for (int chunk = 0; chunk*32 <= maxIdx; ++chunk) {
    __syncthreads();                         // prior chunk / encoder reads of rnnS done
    *(float4*)&rnnS[pfR*292 + pfP*4] = pf;   // commit prefetched chunk
    if ((chunk + 1)*32 <= maxIdx) pf = rnnRow[(chunk + 1)*72];  // issue next early
    __syncthreads();
    if (doXt) hF[0][xtDst] = f2h(rnnS[xtSrc]);   // xt for first step of chunk (par==0)
    __syncthreads();
    const int lim = min(31, maxIdx - chunk*32);
    int tc = 0;
    while (tc + 1 <= lim) { STEP(0) STEP(1) }
    if (tc <= lim) { STEP(0) }               // odd tail only possible on the last chunk
  }
#undef STEP
#undef MFMA16

  // ---------------- decoder: 72 -> 288 -> 288 -> 8 ----------------
  if (t < NR) dS[t] = deltas[brS[t]*TT + idxS[t]];
  __syncthreads();

  { // build dec_in into hS[u][r]  (576 elements, one per thread)
    int u = t % 72, r = t / 72;
    float d = dS[r];
    float sp = snapP[r][u], sc = snapC[r][u];
    hS[u*8 + r] = fmaf(d, sc - sp, sp);
  }
  __syncthreads();

  // layer1: 288 x 72  (all 576 threads: n = t>>1, half-row rh)
  float* d1S = rnnS; // [n][8]
  {
    int n = t >> 1, rh = (t & 1)*4;
    float acc[4];
    float b = db1[n];
    acc[0]=b; acc[1]=b; acc[2]=b; acc[3]=b;
    const float4* w4 = (const float4*)(dW1 + n*HH);
    #pragma unroll 2
    for (int k4 = 0; k4 < 18; ++k4) {
      float4 w = w4[k4];
      FMA4(acc, w.x, &hS[(4*k4+0)*8 + rh]);
      FMA4(acc, w.y, &hS[(4*k4+1)*8 + rh]);
      FMA4(acc, w.z, &hS[(4*k4+2)*8 + rh]);
      FMA4(acc, w.w, &hS[(4*k4+3)*8 + rh]);
    }
    #pragma unroll
    for (int j = 0; j < 4; ++j) d1S[n*8 + rh + j] = ftanh(acc[j]);
  }
  __syncthreads();

  // layer2: 288 x 288
  float* d2S = gS;   // [n][8]
  {
    int n = t >> 1, rh = (t & 1)*4;
    float acc[4];
    float b = db2[n];
    acc[0]=b; acc[1]=b; acc[2]=b; acc[3]=b;
    const float4* w4 = (const float4*)(dW2 + n*288);
    #pragma unroll 4
    for (int k4 = 0; k4 < 72; ++k4) {
      float4 w = w4[k4];
      FMA4(acc, w.x, &d1S[(4*k4+0)*8 + rh]);
      FMA4(acc, w.y, &d1S[(4*k4+1)*8 + rh]);
      FMA4(acc, w.z, &d1S[(4*k4+2)*8 + rh]);
      FMA4(acc, w.w, &d1S[(4*k4+3)*8 + rh]);
    }
    #pragma unroll
    for (int j = 0; j < 4; ++j) d2S[n*8 + rh + j] = ftanh(acc[j]);
  }
  __syncthreads();

  // layer3: 8 x 288 (linear) + scatter store
  if (t < 64) {
    int o = t & 7, r = t >> 3;
    float acc3 = db3[o];
    const float* wr = dW3 + o*288;
    #pragma unroll 4
    for (int k = 0; k < 288; ++k) acc3 = fmaf(wr[k], d2S[k*8 + r], acc3);
    out[brS[r]*8 + o] = acc3;
  }
}

extern "C" void kernel_launch(void* const* d_in, const int* in_sizes, int n_in,
                              void* d_out, int out_size, void* d_ws, size_t ws_size,
                              hipStream_t stream) {
  const float* x      = (const float*)d_in[0];
  const float* rnn    = (const float*)d_in[1];
  const float* deltas = (const float*)d_in[2];
  const int*   h_lens = (const int*)  d_in[3];
  const float* W_ih   = (const float*)d_in[4];
  const float* W_hh   = (const float*)d_in[5];
  const float* b_ih   = (const float*)d_in[6];
  const float* b_hh   = (const float*)d_in[7];
  const float* eW1    = (const float*)d_in[8];
  const float* eb1    = (const float*)d_in[9];
  const float* eW2    = (const float*)d_in[10];
  const float* eb2    = (const float*)d_in[11];
  const float* eW3    = (const float*)d_in[12];
  const float* eb3    = (const float*)d_in[13];
  const float* dW1    = (const float*)d_in[14];
  const float* db1    = (const float*)d_in[15];
  const float* dW2    = (const float*)d_in[16];
  const float* db2    = (const float*)d_in[17];
  const float* dW3    = (const float*)d_in[18];
  const float* db3    = (const float*)d_in[19];
  float* out = (float*)d_out;

  int* perm = nullptr;
  if (ws_size >= 2048 * sizeof(int)) {
    perm = (int*)d_ws;
    cfm_sort<<<1, 256, 0, stream>>>(h_lens, perm);
  }
  cfm_main<<<NBLK, NTH, 0, stream>>>(x, rnn, deltas, h_lens, W_ih, W_hh, b_ih, b_hh,
                                     eW1, eb1, eW2, eb2, eW3, eb3,
                                     dW1, db1, dW2, db2, dW3, db3,
                                     perm, out);
}